// Round 8
// baseline (1687.890 us; speedup 1.0000x reference)
//
#include <hip/hip_runtime.h>
#include <math.h>

__device__ __forceinline__ float sigm(float x) { return 1.0f / (1.0f + __expf(-x)); }

// rank-4 update of acc[64] from one float4 of x and 4 weight rows
#define RANK4(XV, WPTR) do {                                                            \
    const float* w_ = (WPTR);                                                           \
    _Pragma("unroll") for (int o_ = 0; o_ < 64; ++o_) acc[o_] = fmaf((XV).x, w_[o_],       acc[o_]); \
    _Pragma("unroll") for (int o_ = 0; o_ < 64; ++o_) acc[o_] = fmaf((XV).y, w_[64 + o_],  acc[o_]); \
    _Pragma("unroll") for (int o_ = 0; o_ < 64; ++o_) acc[o_] = fmaf((XV).z, w_[128 + o_], acc[o_]); \
    _Pragma("unroll") for (int o_ = 0; o_ < 64; ++o_) acc[o_] = fmaf((XV).w, w_[192 + o_], acc[o_]); \
} while (0)

// ---- LDS layout for the fast edge kernel (float offsets) ----
#define OFF_W1VN  0        // 33*64  = 2112  (w1_ws rows 288..320)
#define OFF_W1ES  2112     // 32*64  = 2048  (w1_ws rows 128..159)
#define OFF_W2    4160     // 68*64  = 4352
#define OFF_W3    8512     // 68*64  = 4352
#define OFF_WHE   12864    // 33     (w1_wh edge column c=16)
#define OFF_W1WV  12897    // 132
#define OFF_W1SB  13029    // 64
#define OFF_W1SV  13093    // 256
#define OFF_W1SVB 13349    // 4
#define OFF_W2WH  13353    // 16
#define OFF_W2SB  13369    // 64
#define OFF_W2WV  13433    // 16
#define OFF_W2SV  13449    // 256
#define OFF_W2SVB 13705    // 4
#define OFF_W3WH  13709    // 16
#define OFF_W3SB  13725    // 64
#define OFF_W3WV  13789    // 16
#define OFF_W3SV  13805    // 256
#define OFF_W3SVB 14061    // 4
#define OFF_ROWS  14080    // 256 rows * 69 floats = 17664
#define LDS_TOT_F (14080 + 256 * 69)   // 31744 floats = 126976 B

// ================= node precompute (unchanged from round 7) =================
__global__ __launch_bounds__(64) void node_pre_kernel(
    const float* __restrict__ node_s, const float* __restrict__ node_v,
    const float* __restrict__ w1_wh, const float* __restrict__ w1_ws,
    float* __restrict__ ysA, float* __restrict__ ysB,
    float* __restrict__ va, float* __restrict__ vb, int N)
{
    const int n = blockIdx.x * 64 + threadIdx.x;
    if (n >= N) return;

    float v[48];
    {
        const float4* vs = (const float4*)(node_v + (size_t)n * 48);
#pragma unroll
        for (int j = 0; j < 12; ++j) {
            float4 t = vs[j];
            v[4 * j + 0] = t.x; v[4 * j + 1] = t.y; v[4 * j + 2] = t.z; v[4 * j + 3] = t.w;
        }
    }
    float* vaP = va + (size_t)n * 100;
    float* vbP = vb + (size_t)n * 100;
    for (int h = 0; h < 33; ++h) {
        const float* wc = w1_wh + h;
        float a0 = 0.f, a1 = 0.f, a2 = 0.f, b0 = 0.f, b1 = 0.f, b2 = 0.f;
#pragma unroll
        for (int c = 0; c < 16; ++c) {
            const float wa = wc[c * 33];
            const float wb = wc[(17 + c) * 33];
            a0 = fmaf(v[3 * c + 0], wa, a0); a1 = fmaf(v[3 * c + 1], wa, a1); a2 = fmaf(v[3 * c + 2], wa, a2);
            b0 = fmaf(v[3 * c + 0], wb, b0); b1 = fmaf(v[3 * c + 1], wb, b1); b2 = fmaf(v[3 * c + 2], wb, b2);
        }
        vaP[3 * h + 0] = a0; vaP[3 * h + 1] = a1; vaP[3 * h + 2] = a2;
        vbP[3 * h + 0] = b0; vbP[3 * h + 1] = b1; vbP[3 * h + 2] = b2;
    }

    const float4* xs = (const float4*)(node_s + (size_t)n * 128);
    {
        float acc[64];
#pragma unroll
        for (int o = 0; o < 64; ++o) acc[o] = 0.0f;
        for (int k4 = 0; k4 < 32; ++k4) { float4 x = xs[k4]; RANK4(x, w1_ws + (k4 * 4) * 64); }
        float4* oa = (float4*)(ysA + (size_t)n * 64);
#pragma unroll
        for (int q = 0; q < 16; ++q) { float4 t; t.x = acc[4*q]; t.y = acc[4*q+1]; t.z = acc[4*q+2]; t.w = acc[4*q+3]; oa[q] = t; }
    }
    {
        float acc[64];
#pragma unroll
        for (int o = 0; o < 64; ++o) acc[o] = 0.0f;
        for (int k4 = 0; k4 < 32; ++k4) { float4 x = xs[k4]; RANK4(x, w1_ws + (160 + k4 * 4) * 64); }
        float4* ob = (float4*)(ysB + (size_t)n * 64);
#pragma unroll
        for (int q = 0; q < 16; ++q) { float4 t; t.x = acc[4*q]; t.y = acc[4*q+1]; t.z = acc[4*q+2]; t.w = acc[4*q+3]; ob[q] = t; }
    }
}

// ================= edge kernel: all weights in LDS (broadcast ds_read) =================
__global__ __launch_bounds__(256, 1) void gvp_edge_fast_kernel(
    const int* __restrict__ ei, const float* __restrict__ edge_s,
    const float* __restrict__ edge_v,
    const float* __restrict__ ysA, const float* __restrict__ ysB,
    const float* __restrict__ va, const float* __restrict__ vb,
    const float* __restrict__ w1_wh, const float* __restrict__ w1_ws,
    const float* __restrict__ w1_wsb, const float* __restrict__ w1_wv,
    const float* __restrict__ w1_wsv, const float* __restrict__ w1_wsvb,
    const float* __restrict__ w2_wh, const float* __restrict__ w2_ws,
    const float* __restrict__ w2_wsb, const float* __restrict__ w2_wv,
    const float* __restrict__ w2_wsv, const float* __restrict__ w2_wsvb,
    const float* __restrict__ w3_wh, const float* __restrict__ w3_ws,
    const float* __restrict__ w3_wsb, const float* __restrict__ w3_wv,
    const float* __restrict__ w3_wsv, const float* __restrict__ w3_wsvb,
    float* __restrict__ out_s, float* __restrict__ out_v,
    float* __restrict__ cnt, int E)
{
    extern __shared__ float S[];
    const int tid = threadIdx.x;

    // ---- stage all weights into LDS (coalesced global reads, linear ds writes)
    {
        const float* sVN = w1_ws + 288 * 64;
        for (int i = tid; i < 2112; i += 256) S[OFF_W1VN + i] = sVN[i];
        const float* sES = w1_ws + 128 * 64;
        for (int i = tid; i < 2048; i += 256) S[OFF_W1ES + i] = sES[i];
        for (int i = tid; i < 4352; i += 256) S[OFF_W2 + i] = w2_ws[i];
        for (int i = tid; i < 4352; i += 256) S[OFF_W3 + i] = w3_ws[i];
        if (tid < 33)  S[OFF_WHE  + tid] = w1_wh[16 * 33 + tid];
        if (tid < 132) S[OFF_W1WV + tid] = w1_wv[tid];
        if (tid < 64)  S[OFF_W1SB + tid] = w1_wsb[tid];
        S[OFF_W1SV + tid] = w1_wsv[tid];          // 256 exact
        if (tid < 4)   S[OFF_W1SVB + tid] = w1_wsvb[tid];
        if (tid < 16)  S[OFF_W2WH + tid] = w2_wh[tid];
        if (tid < 64)  S[OFF_W2SB + tid] = w2_wsb[tid];
        if (tid < 16)  S[OFF_W2WV + tid] = w2_wv[tid];
        S[OFF_W2SV + tid] = w2_wsv[tid];          // 256 exact
        if (tid < 4)   S[OFF_W2SVB + tid] = w2_wsvb[tid];
        if (tid < 16)  S[OFF_W3WH + tid] = w3_wh[tid];
        if (tid < 64)  S[OFF_W3SB + tid] = w3_wsb[tid];
        if (tid < 16)  S[OFF_W3WV + tid] = w3_wv[tid];
        S[OFF_W3SV + tid] = w3_wsv[tid];          // 256 exact
        if (tid < 4)   S[OFF_W3SVB + tid] = w3_wsvb[tid];
    }
    __syncthreads();

    const int e = blockIdx.x * 256 + tid;
    if (e >= E) return;

    float* row = S + OFF_ROWS + tid * 69;   // per-thread private row (sr|vn), stride 69 -> bank-spread
    const int src = ei[e];
    const int dst = ei[E + e];
    const float ev0 = edge_v[(size_t)e * 3 + 0];
    const float ev1 = edge_v[(size_t)e * 3 + 1];
    const float ev2 = edge_v[(size_t)e * 3 + 2];

    // ---- phase V: vh[h] = va_src + vb_dst + ev*we[h]; vn feeds acc; pv accumulation
    float acc[64];
#pragma unroll
    for (int o = 0; o < 64; ++o) acc[o] = 0.0f;
    float pv[12];
#pragma unroll
    for (int i = 0; i < 12; ++i) pv[i] = 0.0f;

    const float* vaP = va + (size_t)src * 100;
    const float* vbP = vb + (size_t)dst * 100;
    for (int g = 0; g < 8; ++g) {            // h = 4g..4g+3
        float ca[12];
        {
            float4 A0 = *(const float4*)(vaP + g * 12 + 0);
            float4 A1 = *(const float4*)(vaP + g * 12 + 4);
            float4 A2 = *(const float4*)(vaP + g * 12 + 8);
            float4 B0 = *(const float4*)(vbP + g * 12 + 0);
            float4 B1 = *(const float4*)(vbP + g * 12 + 4);
            float4 B2 = *(const float4*)(vbP + g * 12 + 8);
            ca[0] = A0.x + B0.x; ca[1] = A0.y + B0.y; ca[2]  = A0.z + B0.z; ca[3]  = A0.w + B0.w;
            ca[4] = A1.x + B1.x; ca[5] = A1.y + B1.y; ca[6]  = A1.z + B1.z; ca[7]  = A1.w + B1.w;
            ca[8] = A2.x + B2.x; ca[9] = A2.y + B2.y; ca[10] = A2.z + B2.z; ca[11] = A2.w + B2.w;
        }
        const float* weP = S + OFF_WHE + 4 * g;
        const float* wvP = S + OFF_W1WV + (4 * g) * 4;
#pragma unroll
        for (int i = 0; i < 4; ++i) {
            const float we = weP[i];
            const float d0 = ca[3 * i + 0] + ev0 * we;
            const float d1 = ca[3 * i + 1] + ev1 * we;
            const float d2 = ca[3 * i + 2] + ev2 * we;
            const float vn = sqrtf(fmaxf(d0 * d0 + d1 * d1 + d2 * d2, 1e-8f));
            const float* wr = S + OFF_W1VN + (4 * g + i) * 64;   // uniform LDS -> broadcast
#pragma unroll
            for (int o = 0; o < 64; ++o) acc[o] = fmaf(vn, wr[o], acc[o]);
#pragma unroll
            for (int vo = 0; vo < 4; ++vo) {
                const float w = wvP[i * 4 + vo];
                pv[vo * 3 + 0] = fmaf(d0, w, pv[vo * 3 + 0]);
                pv[vo * 3 + 1] = fmaf(d1, w, pv[vo * 3 + 1]);
                pv[vo * 3 + 2] = fmaf(d2, w, pv[vo * 3 + 2]);
            }
        }
    }
    {   // tail h = 32
        float4 A = *(const float4*)(vaP + 96);
        float4 B = *(const float4*)(vbP + 96);
        const float we = S[OFF_WHE + 32];
        const float d0 = A.x + B.x + ev0 * we;
        const float d1 = A.y + B.y + ev1 * we;
        const float d2 = A.z + B.z + ev2 * we;
        const float vn = sqrtf(fmaxf(d0 * d0 + d1 * d1 + d2 * d2, 1e-8f));
        const float* wr = S + OFF_W1VN + 32 * 64;
#pragma unroll
        for (int o = 0; o < 64; ++o) acc[o] = fmaf(vn, wr[o], acc[o]);
#pragma unroll
        for (int vo = 0; vo < 4; ++vo) {
            const float w = S[OFF_W1WV + 32 * 4 + vo];
            pv[vo * 3 + 0] = fmaf(d0, w, pv[vo * 3 + 0]);
            pv[vo * 3 + 1] = fmaf(d1, w, pv[vo * 3 + 1]);
            pv[vo * 3 + 2] = fmaf(d2, w, pv[vo * 3 + 2]);
        }
    }

    // ---- add precomputed node terms
    {
        const float4* pa = (const float4*)(ysA + (size_t)src * 64);
        const float4* pb = (const float4*)(ysB + (size_t)dst * 64);
#pragma unroll
        for (int q = 0; q < 16; ++q) {
            float4 xa = pa[q], xb = pb[q];
            acc[4 * q + 0] += xa.x + xb.x;
            acc[4 * q + 1] += xa.y + xb.y;
            acc[4 * q + 2] += xa.z + xb.z;
            acc[4 * q + 3] += xa.w + xb.w;
        }
    }
    // ---- edge_s @ w1_ws[128:160]  (weights from LDS)
    {
        const float4* xs = (const float4*)(edge_s + (size_t)e * 32);
        for (int k4 = 0; k4 < 8; ++k4) { float4 x = xs[k4]; RANK4(x, S + OFF_W1ES + (k4 * 4) * 64); }
    }

    // ---- layer-1 epilogue: gate1, relu -> row[0..63], vn2 -> row[64..67]
    float gp[4] = {0.f, 0.f, 0.f, 0.f};
#pragma unroll
    for (int o = 0; o < 64; ++o) {
        const float s = acc[o] + S[OFF_W1SB + o];
        const float sg = sigm(s);
#pragma unroll
        for (int vo = 0; vo < 4; ++vo) gp[vo] = fmaf(sg, S[OFF_W1SV + o * 4 + vo], gp[vo]);
        row[o] = fmaxf(s, 0.0f);
    }
    float g1[4];
#pragma unroll
    for (int vo = 0; vo < 4; ++vo) g1[vo] = sigm(gp[vo] + S[OFF_W1SVB + vo]);
    float v1g[12];
#pragma unroll
    for (int vo = 0; vo < 4; ++vo)
#pragma unroll
        for (int d = 0; d < 3; ++d) v1g[vo * 3 + d] = pv[vo * 3 + d] * g1[vo];
    float vh2[12];
#pragma unroll
    for (int i = 0; i < 12; ++i) vh2[i] = 0.0f;
#pragma unroll
    for (int c = 0; c < 4; ++c)
#pragma unroll
        for (int h = 0; h < 4; ++h) {
            const float w = S[OFF_W2WH + c * 4 + h];
#pragma unroll
            for (int d = 0; d < 3; ++d) vh2[d * 4 + h] = fmaf(v1g[c * 3 + d], w, vh2[d * 4 + h]);
        }
#pragma unroll
    for (int h = 0; h < 4; ++h) {
        const float ss = vh2[h] * vh2[h] + vh2[4 + h] * vh2[4 + h] + vh2[8 + h] * vh2[8 + h];
        row[64 + h] = sqrtf(fmaxf(ss, 1e-8f));
    }

    // ---- GEMM2 (weights from LDS, broadcast reads)
    float acc2[64];
#pragma unroll
    for (int o = 0; o < 64; ++o) acc2[o] = 0.0f;
    for (int k = 0; k < 68; ++k) {
        const float xk = row[k];
        const float* w = S + OFF_W2 + k * 64;
#pragma unroll
        for (int o = 0; o < 64; ++o) acc2[o] = fmaf(xk, w[o], acc2[o]);
    }

    // ---- layer-2 epilogue
    float gp2[4] = {0.f, 0.f, 0.f, 0.f};
#pragma unroll
    for (int o = 0; o < 64; ++o) {
        const float s = acc2[o] + S[OFF_W2SB + o];
        const float sg = sigm(s);
#pragma unroll
        for (int vo = 0; vo < 4; ++vo) gp2[vo] = fmaf(sg, S[OFF_W2SV + o * 4 + vo], gp2[vo]);
        row[o] = fmaxf(s, 0.0f);
    }
    float g2[4];
#pragma unroll
    for (int vo = 0; vo < 4; ++vo) g2[vo] = sigm(gp2[vo] + S[OFF_W2SVB + vo]);
    float v2g[12];
#pragma unroll
    for (int vo = 0; vo < 4; ++vo)
#pragma unroll
        for (int d = 0; d < 3; ++d) {
            float t = 0.0f;
#pragma unroll
            for (int h = 0; h < 4; ++h) t = fmaf(vh2[d * 4 + h], S[OFF_W2WV + h * 4 + vo], t);
            v2g[vo * 3 + d] = t * g2[vo];
        }
    float vh3[12];
#pragma unroll
    for (int i = 0; i < 12; ++i) vh3[i] = 0.0f;
#pragma unroll
    for (int c = 0; c < 4; ++c)
#pragma unroll
        for (int h = 0; h < 4; ++h) {
            const float w = S[OFF_W3WH + c * 4 + h];
#pragma unroll
            for (int d = 0; d < 3; ++d) vh3[d * 4 + h] = fmaf(v2g[c * 3 + d], w, vh3[d * 4 + h]);
        }
#pragma unroll
    for (int h = 0; h < 4; ++h) {
        const float ss = vh3[h] * vh3[h] + vh3[4 + h] * vh3[4 + h] + vh3[8 + h] * vh3[8 + h];
        row[64 + h] = sqrtf(fmaxf(ss, 1e-8f));
    }

    // ---- GEMM3 (weights from LDS)
#pragma unroll
    for (int o = 0; o < 64; ++o) acc[o] = 0.0f;
    for (int k = 0; k < 68; ++k) {
        const float xk = row[k];
        const float* w = S + OFF_W3 + k * 64;
#pragma unroll
        for (int o = 0; o < 64; ++o) acc[o] = fmaf(xk, w[o], acc[o]);
    }

    // ---- final epilogue + atomics
    float gp3[4] = {0.f, 0.f, 0.f, 0.f};
#pragma unroll
    for (int o = 0; o < 64; ++o) {
        const float s3 = acc[o] + S[OFF_W3SB + o];
#pragma unroll
        for (int vo = 0; vo < 4; ++vo) gp3[vo] = fmaf(s3, S[OFF_W3SV + o * 4 + vo], gp3[vo]);
        atomicAdd(&out_s[(size_t)dst * 64 + o], s3);
    }
    float g3[4];
#pragma unroll
    for (int vo = 0; vo < 4; ++vo) g3[vo] = sigm(gp3[vo] + S[OFF_W3SVB + vo]);
#pragma unroll
    for (int vo = 0; vo < 4; ++vo)
#pragma unroll
        for (int d = 0; d < 3; ++d) {
            float t = 0.0f;
#pragma unroll
            for (int h = 0; h < 4; ++h) t = fmaf(vh3[d * 4 + h], S[OFF_W3WV + h * 4 + vo], t);
            atomicAdd(&out_v[(size_t)dst * 12 + vo * 3 + d], t * g3[vo]);
        }
    atomicAdd(&cnt[dst], 1.0f);
}

// ================= legacy edge kernel (round-3 passing version; fallback if ws too small) =================
__global__ __launch_bounds__(128) void gvp_edge_kernel(
    const float* __restrict__ node_s, const float* __restrict__ node_v,
    const int* __restrict__ ei, const float* __restrict__ edge_s,
    const float* __restrict__ edge_v,
    const float* __restrict__ w1_wh, const float* __restrict__ w1_ws,
    const float* __restrict__ w1_wsb, const float* __restrict__ w1_wv,
    const float* __restrict__ w1_wsv, const float* __restrict__ w1_wsvb,
    const float* __restrict__ w2_wh, const float* __restrict__ w2_ws,
    const float* __restrict__ w2_wsb, const float* __restrict__ w2_wv,
    const float* __restrict__ w2_wsv, const float* __restrict__ w2_wsvb,
    const float* __restrict__ w3_wh, const float* __restrict__ w3_ws,
    const float* __restrict__ w3_wsb, const float* __restrict__ w3_wv,
    const float* __restrict__ w3_wsv, const float* __restrict__ w3_wsvb,
    float* __restrict__ out_s, float* __restrict__ out_v,
    float* __restrict__ cnt, int E)
{
    __shared__ float rows[128 * 99];
    float* row = rows + threadIdx.x * 99;
    const int e = blockIdx.x * 128 + threadIdx.x;
    if (e >= E) return;
    const int src = ei[e];
    const int dst = ei[E + e];
    {
        const float* a = node_v + (size_t)src * 48;
        const float* b = node_v + (size_t)dst * 48;
#pragma unroll
        for (int j = 0; j < 48; j += 4) {
            float4 vav = *(const float4*)(a + j);
            row[j + 0] = vav.x; row[j + 1] = vav.y; row[j + 2] = vav.z; row[j + 3] = vav.w;
            float4 vbv = *(const float4*)(b + j);
            row[48 + j + 0] = vbv.x; row[48 + j + 1] = vbv.y; row[48 + j + 2] = vbv.z; row[48 + j + 3] = vbv.w;
        }
        row[96] = edge_v[(size_t)e * 3 + 0];
        row[97] = edge_v[(size_t)e * 3 + 1];
        row[98] = edge_v[(size_t)e * 3 + 2];
    }
    float vn[33];
    float pv[12];
#pragma unroll
    for (int i = 0; i < 12; ++i) pv[i] = 0.0f;
#pragma unroll
    for (int p = 0; p < 3; ++p) {
        const int h0 = p * 11;
        float a0[11], a1[11], a2[11];
#pragma unroll
        for (int i = 0; i < 11; ++i) { a0[i] = 0.f; a1[i] = 0.f; a2[i] = 0.f; }
        for (int c = 0; c < 16; ++c) {
            const float v0 = row[3 * c + 0], v1 = row[3 * c + 1], v2 = row[3 * c + 2];
            const float* wr = w1_wh + c * 33 + h0;
#pragma unroll
            for (int i = 0; i < 11; ++i) {
                const float w = wr[i];
                a0[i] = fmaf(v0, w, a0[i]); a1[i] = fmaf(v1, w, a1[i]); a2[i] = fmaf(v2, w, a2[i]);
            }
        }
        for (int c = 0; c < 16; ++c) {
            const float v0 = row[48 + 3 * c + 0], v1 = row[48 + 3 * c + 1], v2 = row[48 + 3 * c + 2];
            const float* wr = w1_wh + (17 + c) * 33 + h0;
#pragma unroll
            for (int i = 0; i < 11; ++i) {
                const float w = wr[i];
                a0[i] = fmaf(v0, w, a0[i]); a1[i] = fmaf(v1, w, a1[i]); a2[i] = fmaf(v2, w, a2[i]);
            }
        }
        {
            const float v0 = row[96], v1 = row[97], v2 = row[98];
            const float* wr = w1_wh + 16 * 33 + h0;
#pragma unroll
            for (int i = 0; i < 11; ++i) {
                const float w = wr[i];
                a0[i] = fmaf(v0, w, a0[i]); a1[i] = fmaf(v1, w, a1[i]); a2[i] = fmaf(v2, w, a2[i]);
            }
        }
#pragma unroll
        for (int i = 0; i < 11; ++i) {
            const int h = h0 + i;
            vn[h] = sqrtf(fmaxf(a0[i] * a0[i] + a1[i] * a1[i] + a2[i] * a2[i], 1e-8f));
#pragma unroll
            for (int vo = 0; vo < 4; ++vo) {
                const float w = w1_wv[h * 4 + vo];
                pv[vo * 3 + 0] = fmaf(a0[i], w, pv[vo * 3 + 0]);
                pv[vo * 3 + 1] = fmaf(a1[i], w, pv[vo * 3 + 1]);
                pv[vo * 3 + 2] = fmaf(a2[i], w, pv[vo * 3 + 2]);
            }
        }
    }
#pragma unroll
    for (int h = 0; h < 33; ++h) row[h] = vn[h];
    float acc[64];
#pragma unroll
    for (int o = 0; o < 64; ++o) acc[o] = 0.0f;
    {
        const float4* xs = (const float4*)(node_s + (size_t)src * 128);
        for (int k4 = 0; k4 < 32; ++k4) { float4 x = xs[k4]; RANK4(x, w1_ws + (k4 * 4) * 64); }
    }
    {
        const float4* xs = (const float4*)(edge_s + (size_t)e * 32);
        for (int k4 = 0; k4 < 8; ++k4)  { float4 x = xs[k4]; RANK4(x, w1_ws + (128 + k4 * 4) * 64); }
    }
    {
        const float4* xs = (const float4*)(node_s + (size_t)dst * 128);
        for (int k4 = 0; k4 < 32; ++k4) { float4 x = xs[k4]; RANK4(x, w1_ws + (160 + k4 * 4) * 64); }
    }
    for (int h = 0; h < 33; ++h) {
        const float xk = row[h];
        const float* w = w1_ws + (288 + h) * 64;
#pragma unroll
        for (int o = 0; o < 64; ++o) acc[o] = fmaf(xk, w[o], acc[o]);
    }
    float gp[4] = {0.f, 0.f, 0.f, 0.f};
#pragma unroll
    for (int o = 0; o < 64; ++o) {
        const float s = acc[o] + w1_wsb[o];
        const float sg = sigm(s);
#pragma unroll
        for (int vo = 0; vo < 4; ++vo) gp[vo] = fmaf(sg, w1_wsv[o * 4 + vo], gp[vo]);
        row[o] = fmaxf(s, 0.0f);
    }
    float g1[4];
#pragma unroll
    for (int vo = 0; vo < 4; ++vo) g1[vo] = sigm(gp[vo] + w1_wsvb[vo]);
    float v1g[12];
#pragma unroll
    for (int vo = 0; vo < 4; ++vo)
#pragma unroll
        for (int d = 0; d < 3; ++d) v1g[vo * 3 + d] = pv[vo * 3 + d] * g1[vo];
    float vh2[12];
#pragma unroll
    for (int i = 0; i < 12; ++i) vh2[i] = 0.0f;
#pragma unroll
    for (int c = 0; c < 4; ++c)
#pragma unroll
        for (int h = 0; h < 4; ++h) {
            const float w = w2_wh[c * 4 + h];
#pragma unroll
            for (int d = 0; d < 3; ++d) vh2[d * 4 + h] = fmaf(v1g[c * 3 + d], w, vh2[d * 4 + h]);
        }
#pragma unroll
    for (int h = 0; h < 4; ++h) {
        const float ss = vh2[h] * vh2[h] + vh2[4 + h] * vh2[4 + h] + vh2[8 + h] * vh2[8 + h];
        row[64 + h] = sqrtf(fmaxf(ss, 1e-8f));
    }
    float acc2[64];
#pragma unroll
    for (int o = 0; o < 64; ++o) acc2[o] = 0.0f;
    for (int k = 0; k < 68; ++k) {
        const float xk = row[k];
        const float* w = w2_ws + k * 64;
#pragma unroll
        for (int o = 0; o < 64; ++o) acc2[o] = fmaf(xk, w[o], acc2[o]);
    }
    float gp2[4] = {0.f, 0.f, 0.f, 0.f};
#pragma unroll
    for (int o = 0; o < 64; ++o) {
        const float s = acc2[o] + w2_wsb[o];
        const float sg = sigm(s);
#pragma unroll
        for (int vo = 0; vo < 4; ++vo) gp2[vo] = fmaf(sg, w2_wsv[o * 4 + vo], gp2[vo]);
        row[o] = fmaxf(s, 0.0f);
    }
    float g2[4];
#pragma unroll
    for (int vo = 0; vo < 4; ++vo) g2[vo] = sigm(gp2[vo] + w2_wsvb[vo]);
    float v2g[12];
#pragma unroll
    for (int vo = 0; vo < 4; ++vo)
#pragma unroll
        for (int d = 0; d < 3; ++d) {
            float t = 0.0f;
#pragma unroll
            for (int h = 0; h < 4; ++h) t = fmaf(vh2[d * 4 + h], w2_wv[h * 4 + vo], t);
            v2g[vo * 3 + d] = t * g2[vo];
        }
    float vh3[12];
#pragma unroll
    for (int i = 0; i < 12; ++i) vh3[i] = 0.0f;
#pragma unroll
    for (int c = 0; c < 4; ++c)
#pragma unroll
        for (int h = 0; h < 4; ++h) {
            const float w = w3_wh[c * 4 + h];
#pragma unroll
            for (int d = 0; d < 3; ++d) vh3[d * 4 + h] = fmaf(v2g[c * 3 + d], w, vh3[d * 4 + h]);
        }
#pragma unroll
    for (int h = 0; h < 4; ++h) {
        const float ss = vh3[h] * vh3[h] + vh3[4 + h] * vh3[4 + h] + vh3[8 + h] * vh3[8 + h];
        row[64 + h] = sqrtf(fmaxf(ss, 1e-8f));
    }
#pragma unroll
    for (int o = 0; o < 64; ++o) acc[o] = 0.0f;
    for (int k = 0; k < 68; ++k) {
        const float xk = row[k];
        const float* w = w3_ws + k * 64;
#pragma unroll
        for (int o = 0; o < 64; ++o) acc[o] = fmaf(xk, w[o], acc[o]);
    }
    float gp3[4] = {0.f, 0.f, 0.f, 0.f};
#pragma unroll
    for (int o = 0; o < 64; ++o) {
        const float s3 = acc[o] + w3_wsb[o];
#pragma unroll
        for (int vo = 0; vo < 4; ++vo) gp3[vo] = fmaf(s3, w3_wsv[o * 4 + vo], gp3[vo]);
        atomicAdd(&out_s[(size_t)dst * 64 + o], s3);
    }
    float g3[4];
#pragma unroll
    for (int vo = 0; vo < 4; ++vo) g3[vo] = sigm(gp3[vo] + w3_wsvb[vo]);
#pragma unroll
    for (int vo = 0; vo < 4; ++vo)
#pragma unroll
        for (int d = 0; d < 3; ++d) {
            float t = 0.0f;
#pragma unroll
            for (int h = 0; h < 4; ++h) t = fmaf(vh3[d * 4 + h], w3_wv[h * 4 + vo], t);
            atomicAdd(&out_v[(size_t)dst * 12 + vo * 3 + d], t * g3[vo]);
        }
    atomicAdd(&cnt[dst], 1.0f);
}

// ================= finalize =================
__global__ void gvp_finalize_kernel(float* __restrict__ out,
                                    const float* __restrict__ cnt,
                                    const int* __restrict__ mask, int N)
{
    const int g = blockIdx.x * blockDim.x + threadIdx.x;
    const int ns = N * 64;
    const int total = ns + N * 4;
    if (g >= total) return;
    if (g < ns) {
        const int n = g >> 6, j = g & 63;
        const float denom = fmaxf(cnt[n], 1.0f);
        const float m = (mask[n] != 0) ? 1.0f : 0.0f;
        const float s = out[g] / denom;
        const float r = (j < 7) ? __cosf(s) : (j < 14) ? __sinf(s) : __expf(s);
        out[g] = r * m;
    } else {
        const int g2 = g - ns;
        const int n = g2 >> 2, vo = g2 & 3;
        const float denom = fmaxf(cnt[n], 1.0f);
        const float m = (mask[n] != 0) ? 1.0f : 0.0f;
        float* vp = out + ns + (size_t)n * 12 + vo * 3;
        const float v0 = vp[0] / denom, v1 = vp[1] / denom, v2 = vp[2] / denom;
        const float mag = sqrtf(v0 * v0 + v1 * v1 + v2 * v2);
        const float inv = m / (mag + 1e-8f);
        vp[0] = v0 * inv; vp[1] = v1 * inv; vp[2] = v2 * inv;
    }
}

extern "C" void kernel_launch(void* const* d_in, const int* in_sizes, int n_in,
                              void* d_out, int out_size, void* d_ws, size_t ws_size,
                              hipStream_t stream)
{
    const float* node_s = (const float*)d_in[0];
    const float* node_v = (const float*)d_in[1];
    const int*   ei     = (const int*)d_in[2];
    const float* edge_s = (const float*)d_in[3];
    const float* edge_v = (const float*)d_in[4];
    const int*   mask   = (const int*)d_in[5];
    const float* w1_wh  = (const float*)d_in[6];
    const float* w1_ws  = (const float*)d_in[7];
    const float* w1_wsb = (const float*)d_in[8];
    const float* w1_wv  = (const float*)d_in[9];
    const float* w1_wsv = (const float*)d_in[10];
    const float* w1_wsvb= (const float*)d_in[11];
    const float* w2_wh  = (const float*)d_in[12];
    const float* w2_ws  = (const float*)d_in[13];
    const float* w2_wsb = (const float*)d_in[14];
    const float* w2_wv  = (const float*)d_in[15];
    const float* w2_wsv = (const float*)d_in[16];
    const float* w2_wsvb= (const float*)d_in[17];
    const float* w3_wh  = (const float*)d_in[18];
    const float* w3_ws  = (const float*)d_in[19];
    const float* w3_wsb = (const float*)d_in[20];
    const float* w3_wv  = (const float*)d_in[21];
    const float* w3_wsv = (const float*)d_in[22];
    const float* w3_wsvb= (const float*)d_in[23];

    const int N = in_sizes[0] / 128;   // 20000
    const int E = in_sizes[3] / 32;    // 320000

    float* out = (float*)d_out;
    float* ws  = (float*)d_ws;

    // ws layout (floats): ysA[N*64] | ysB[N*64] | va[N*100] | vb[N*100] | cnt[N]
    const size_t oYA = 0;
    const size_t oYB = (size_t)N * 64;
    const size_t oVA = oYB + (size_t)N * 64;
    const size_t oVB = oVA + (size_t)N * 100;
    const size_t oCN = oVB + (size_t)N * 100;
    const size_t needF = oCN + (size_t)N;
    const bool fast = (ws_size >= needF * sizeof(float));

    hipMemsetAsync(d_out, 0, (size_t)out_size * sizeof(float), stream);

    if (fast) {
        float* cnt = ws + oCN;
        hipMemsetAsync(cnt, 0, (size_t)N * sizeof(float), stream);
        node_pre_kernel<<<(N + 63) / 64, 64, 0, stream>>>(
            node_s, node_v, w1_wh, w1_ws,
            ws + oYA, ws + oYB, ws + oVA, ws + oVB, N);
        const int ldsBytes = LDS_TOT_F * 4;   // 126976 B
        hipFuncSetAttribute((const void*)gvp_edge_fast_kernel,
                            hipFuncAttributeMaxDynamicSharedMemorySize, ldsBytes);
        gvp_edge_fast_kernel<<<(E + 255) / 256, 256, ldsBytes, stream>>>(
            ei, edge_s, edge_v,
            ws + oYA, ws + oYB, ws + oVA, ws + oVB,
            w1_wh, w1_ws, w1_wsb, w1_wv, w1_wsv, w1_wsvb,
            w2_wh, w2_ws, w2_wsb, w2_wv, w2_wsv, w2_wsvb,
            w3_wh, w3_ws, w3_wsb, w3_wv, w3_wsv, w3_wsvb,
            out, out + (size_t)N * 64, cnt, E);
        const int total2 = N * 68;
        gvp_finalize_kernel<<<(total2 + 255) / 256, 256, 0, stream>>>(out, cnt, mask, N);
    } else {
        float* cnt = ws;
        hipMemsetAsync(cnt, 0, (size_t)N * sizeof(float), stream);
        gvp_edge_kernel<<<(E + 127) / 128, 128, 0, stream>>>(
            node_s, node_v, ei, edge_s, edge_v,
            w1_wh, w1_ws, w1_wsb, w1_wv, w1_wsv, w1_wsvb,
            w2_wh, w2_ws, w2_wsb, w2_wv, w2_wsv, w2_wsvb,
            w3_wh, w3_ws, w3_wsb, w3_wv, w3_wsv, w3_wsvb,
            out, out + (size_t)N * 64, cnt, E);
        const int total2 = N * 68;
        gvp_finalize_kernel<<<(total2 + 255) / 256, 256, 0, stream>>>(out, cnt, mask, N);
    }
}

// Round 9
// 691.048 us; speedup vs baseline: 2.4425x; 2.4425x over previous
//
#include <hip/hip_runtime.h>
#include <math.h>

__device__ __forceinline__ float sigm(float x) { return 1.0f / (1.0f + __expf(-x)); }

// rank-4 update of acc[64] from one float4 of x and 4 weight rows (uniform addr)
#define RANK4(XV, WPTR) do {                                                            \
    const float* w_ = (WPTR);                                                           \
    _Pragma("unroll") for (int o_ = 0; o_ < 64; ++o_) acc[o_] = fmaf((XV).x, w_[o_],       acc[o_]); \
    _Pragma("unroll") for (int o_ = 0; o_ < 64; ++o_) acc[o_] = fmaf((XV).y, w_[64 + o_],  acc[o_]); \
    _Pragma("unroll") for (int o_ = 0; o_ < 64; ++o_) acc[o_] = fmaf((XV).z, w_[128 + o_], acc[o_]); \
    _Pragma("unroll") for (int o_ = 0; o_ < 64; ++o_) acc[o_] = fmaf((XV).w, w_[192 + o_], acc[o_]); \
} while (0)

// ================= node precompute (unchanged) =================
__global__ __launch_bounds__(64) void node_pre_kernel(
    const float* __restrict__ node_s, const float* __restrict__ node_v,
    const float* __restrict__ w1_wh, const float* __restrict__ w1_ws,
    float* __restrict__ ysA, float* __restrict__ ysB,
    float* __restrict__ va, float* __restrict__ vb, int N)
{
    const int n = blockIdx.x * 64 + threadIdx.x;
    if (n >= N) return;

    float v[48];
    {
        const float4* vs = (const float4*)(node_v + (size_t)n * 48);
#pragma unroll
        for (int j = 0; j < 12; ++j) {
            float4 t = vs[j];
            v[4 * j + 0] = t.x; v[4 * j + 1] = t.y; v[4 * j + 2] = t.z; v[4 * j + 3] = t.w;
        }
    }
    float* vaP = va + (size_t)n * 100;
    float* vbP = vb + (size_t)n * 100;
    for (int h = 0; h < 33; ++h) {
        const float* wc = w1_wh + h;
        float a0 = 0.f, a1 = 0.f, a2 = 0.f, b0 = 0.f, b1 = 0.f, b2 = 0.f;
#pragma unroll
        for (int c = 0; c < 16; ++c) {
            const float wa = wc[c * 33];
            const float wb = wc[(17 + c) * 33];
            a0 = fmaf(v[3 * c + 0], wa, a0); a1 = fmaf(v[3 * c + 1], wa, a1); a2 = fmaf(v[3 * c + 2], wa, a2);
            b0 = fmaf(v[3 * c + 0], wb, b0); b1 = fmaf(v[3 * c + 1], wb, b1); b2 = fmaf(v[3 * c + 2], wb, b2);
        }
        vaP[3 * h + 0] = a0; vaP[3 * h + 1] = a1; vaP[3 * h + 2] = a2;
        vbP[3 * h + 0] = b0; vbP[3 * h + 1] = b1; vbP[3 * h + 2] = b2;
    }

    const float4* xs = (const float4*)(node_s + (size_t)n * 128);
    {
        float acc[64];
#pragma unroll
        for (int o = 0; o < 64; ++o) acc[o] = 0.0f;
        for (int k4 = 0; k4 < 32; ++k4) { float4 x = xs[k4]; RANK4(x, w1_ws + (k4 * 4) * 64); }
        float4* oa = (float4*)(ysA + (size_t)n * 64);
#pragma unroll
        for (int q = 0; q < 16; ++q) { float4 t; t.x = acc[4*q]; t.y = acc[4*q+1]; t.z = acc[4*q+2]; t.w = acc[4*q+3]; oa[q] = t; }
    }
    {
        float acc[64];
#pragma unroll
        for (int o = 0; o < 64; ++o) acc[o] = 0.0f;
        for (int k4 = 0; k4 < 32; ++k4) { float4 x = xs[k4]; RANK4(x, w1_ws + (160 + k4 * 4) * 64); }
        float4* ob = (float4*)(ysB + (size_t)n * 64);
#pragma unroll
        for (int q = 0; q < 16; ++q) { float4 t; t.x = acc[4*q]; t.y = acc[4*q+1]; t.z = acc[4*q+2]; t.w = acc[4*q+3]; ob[q] = t; }
    }
}

// ================= edge kernel: scatter results, 1 atomic/edge =================
__global__ __launch_bounds__(64) void gvp_edge_scatter_kernel(
    const int* __restrict__ ei, const float* __restrict__ edge_s,
    const float* __restrict__ edge_v,
    const float* __restrict__ ysA, const float* __restrict__ ysB,
    const float* __restrict__ va, const float* __restrict__ vb,
    const float* __restrict__ w1_wh, const float* __restrict__ w1_ws,
    const float* __restrict__ w1_wsb, const float* __restrict__ w1_wv,
    const float* __restrict__ w1_wsv, const float* __restrict__ w1_wsvb,
    const float* __restrict__ w2_wh, const float* __restrict__ w2_ws,
    const float* __restrict__ w2_wsb, const float* __restrict__ w2_wv,
    const float* __restrict__ w2_wsv, const float* __restrict__ w2_wsvb,
    const float* __restrict__ w3_wh, const float* __restrict__ w3_ws,
    const float* __restrict__ w3_wsb, const float* __restrict__ w3_wv,
    const float* __restrict__ w3_wsv, const float* __restrict__ w3_wsvb,
    float* __restrict__ payload, int* __restrict__ slotCnt,
    int* __restrict__ slotTab, float* __restrict__ accS,
    float* __restrict__ accV, int E)
{
    __shared__ float rows[64 * 69];
    float* row = rows + threadIdx.x * 69;
    const int e = blockIdx.x * 64 + threadIdx.x;
    if (e >= E) return;
    const int src = ei[e];
    const int dst = ei[E + e];

    // slot reservation early: RMW latency hides under all the compute below
    const int slot = atomicAdd(&slotCnt[dst], 1);
    if (slot < 64) slotTab[(size_t)dst * 64 + slot] = e;
    const bool ovf = (slot >= 64);

    const float ev0 = edge_v[(size_t)e * 3 + 0];
    const float ev1 = edge_v[(size_t)e * 3 + 1];
    const float ev2 = edge_v[(size_t)e * 3 + 2];

    float acc[64];
#pragma unroll
    for (int o = 0; o < 64; ++o) acc[o] = 0.0f;
    float pv[12];
#pragma unroll
    for (int i = 0; i < 12; ++i) pv[i] = 0.0f;

    const float* vaP = va + (size_t)src * 100;
    const float* vbP = vb + (size_t)dst * 100;
    for (int g = 0; g < 8; ++g) {
        float ca[12];
        {
            float4 A0 = *(const float4*)(vaP + g * 12 + 0);
            float4 A1 = *(const float4*)(vaP + g * 12 + 4);
            float4 A2 = *(const float4*)(vaP + g * 12 + 8);
            float4 B0 = *(const float4*)(vbP + g * 12 + 0);
            float4 B1 = *(const float4*)(vbP + g * 12 + 4);
            float4 B2 = *(const float4*)(vbP + g * 12 + 8);
            ca[0] = A0.x + B0.x; ca[1] = A0.y + B0.y; ca[2]  = A0.z + B0.z; ca[3]  = A0.w + B0.w;
            ca[4] = A1.x + B1.x; ca[5] = A1.y + B1.y; ca[6]  = A1.z + B1.z; ca[7]  = A1.w + B1.w;
            ca[8] = A2.x + B2.x; ca[9] = A2.y + B2.y; ca[10] = A2.z + B2.z; ca[11] = A2.w + B2.w;
        }
        const float* weP = w1_wh + 16 * 33 + 4 * g;
        const float* wvP = w1_wv + (4 * g) * 4;
        const float* wsP = w1_ws + (size_t)(288 + 4 * g) * 64;
#pragma unroll
        for (int i = 0; i < 4; ++i) {
            const float we = weP[i];
            const float d0 = ca[3 * i + 0] + ev0 * we;
            const float d1 = ca[3 * i + 1] + ev1 * we;
            const float d2 = ca[3 * i + 2] + ev2 * we;
            const float vn = sqrtf(fmaxf(d0 * d0 + d1 * d1 + d2 * d2, 1e-8f));
            const float* wr = wsP + i * 64;
#pragma unroll
            for (int o = 0; o < 64; ++o) acc[o] = fmaf(vn, wr[o], acc[o]);
#pragma unroll
            for (int vo = 0; vo < 4; ++vo) {
                const float w = wvP[i * 4 + vo];
                pv[vo * 3 + 0] = fmaf(d0, w, pv[vo * 3 + 0]);
                pv[vo * 3 + 1] = fmaf(d1, w, pv[vo * 3 + 1]);
                pv[vo * 3 + 2] = fmaf(d2, w, pv[vo * 3 + 2]);
            }
        }
    }
    {   // tail h = 32
        float4 A = *(const float4*)(vaP + 96);
        float4 B = *(const float4*)(vbP + 96);
        const float we = w1_wh[16 * 33 + 32];
        const float d0 = A.x + B.x + ev0 * we;
        const float d1 = A.y + B.y + ev1 * we;
        const float d2 = A.z + B.z + ev2 * we;
        const float vn = sqrtf(fmaxf(d0 * d0 + d1 * d1 + d2 * d2, 1e-8f));
        const float* wr = w1_ws + (size_t)320 * 64;
#pragma unroll
        for (int o = 0; o < 64; ++o) acc[o] = fmaf(vn, wr[o], acc[o]);
#pragma unroll
        for (int vo = 0; vo < 4; ++vo) {
            const float w = w1_wv[32 * 4 + vo];
            pv[vo * 3 + 0] = fmaf(d0, w, pv[vo * 3 + 0]);
            pv[vo * 3 + 1] = fmaf(d1, w, pv[vo * 3 + 1]);
            pv[vo * 3 + 2] = fmaf(d2, w, pv[vo * 3 + 2]);
        }
    }

    {
        const float4* pa = (const float4*)(ysA + (size_t)src * 64);
        const float4* pb = (const float4*)(ysB + (size_t)dst * 64);
#pragma unroll
        for (int q = 0; q < 16; ++q) {
            float4 xa = pa[q], xb = pb[q];
            acc[4 * q + 0] += xa.x + xb.x;
            acc[4 * q + 1] += xa.y + xb.y;
            acc[4 * q + 2] += xa.z + xb.z;
            acc[4 * q + 3] += xa.w + xb.w;
        }
    }
    {
        const float4* xs = (const float4*)(edge_s + (size_t)e * 32);
        for (int k4 = 0; k4 < 8; ++k4) { float4 x = xs[k4]; RANK4(x, w1_ws + (size_t)(128 + k4 * 4) * 64); }
    }

    // ---- layer-1 epilogue
    float gp[4] = {0.f, 0.f, 0.f, 0.f};
#pragma unroll
    for (int o = 0; o < 64; ++o) {
        const float s = acc[o] + w1_wsb[o];
        const float sg = sigm(s);
#pragma unroll
        for (int vo = 0; vo < 4; ++vo) gp[vo] = fmaf(sg, w1_wsv[o * 4 + vo], gp[vo]);
        row[o] = fmaxf(s, 0.0f);
    }
    float g1[4];
#pragma unroll
    for (int vo = 0; vo < 4; ++vo) g1[vo] = sigm(gp[vo] + w1_wsvb[vo]);
    float v1g[12];
#pragma unroll
    for (int vo = 0; vo < 4; ++vo)
#pragma unroll
        for (int d = 0; d < 3; ++d) v1g[vo * 3 + d] = pv[vo * 3 + d] * g1[vo];
    float vh2[12];
#pragma unroll
    for (int i = 0; i < 12; ++i) vh2[i] = 0.0f;
#pragma unroll
    for (int c = 0; c < 4; ++c)
#pragma unroll
        for (int h = 0; h < 4; ++h) {
            const float w = w2_wh[c * 4 + h];
#pragma unroll
            for (int d = 0; d < 3; ++d) vh2[d * 4 + h] = fmaf(v1g[c * 3 + d], w, vh2[d * 4 + h]);
        }
#pragma unroll
    for (int h = 0; h < 4; ++h) {
        const float ss = vh2[h] * vh2[h] + vh2[4 + h] * vh2[4 + h] + vh2[8 + h] * vh2[8 + h];
        row[64 + h] = sqrtf(fmaxf(ss, 1e-8f));
    }

    // ---- GEMM2
    float acc2[64];
#pragma unroll
    for (int o = 0; o < 64; ++o) acc2[o] = 0.0f;
    for (int k = 0; k < 68; ++k) {
        const float xk = row[k];
        const float* w = w2_ws + k * 64;
#pragma unroll
        for (int o = 0; o < 64; ++o) acc2[o] = fmaf(xk, w[o], acc2[o]);
    }

    // ---- layer-2 epilogue
    float gp2[4] = {0.f, 0.f, 0.f, 0.f};
#pragma unroll
    for (int o = 0; o < 64; ++o) {
        const float s = acc2[o] + w2_wsb[o];
        const float sg = sigm(s);
#pragma unroll
        for (int vo = 0; vo < 4; ++vo) gp2[vo] = fmaf(sg, w2_wsv[o * 4 + vo], gp2[vo]);
        row[o] = fmaxf(s, 0.0f);
    }
    float g2[4];
#pragma unroll
    for (int vo = 0; vo < 4; ++vo) g2[vo] = sigm(gp2[vo] + w2_wsvb[vo]);
    float v2g[12];
#pragma unroll
    for (int vo = 0; vo < 4; ++vo)
#pragma unroll
        for (int d = 0; d < 3; ++d) {
            float t = 0.0f;
#pragma unroll
            for (int h = 0; h < 4; ++h) t = fmaf(vh2[d * 4 + h], w2_wv[h * 4 + vo], t);
            v2g[vo * 3 + d] = t * g2[vo];
        }
    float vh3[12];
#pragma unroll
    for (int i = 0; i < 12; ++i) vh3[i] = 0.0f;
#pragma unroll
    for (int c = 0; c < 4; ++c)
#pragma unroll
        for (int h = 0; h < 4; ++h) {
            const float w = w3_wh[c * 4 + h];
#pragma unroll
            for (int d = 0; d < 3; ++d) vh3[d * 4 + h] = fmaf(v2g[c * 3 + d], w, vh3[d * 4 + h]);
        }
#pragma unroll
    for (int h = 0; h < 4; ++h) {
        const float ss = vh3[h] * vh3[h] + vh3[4 + h] * vh3[4 + h] + vh3[8 + h] * vh3[8 + h];
        row[64 + h] = sqrtf(fmaxf(ss, 1e-8f));
    }

    // ---- GEMM3
#pragma unroll
    for (int o = 0; o < 64; ++o) acc[o] = 0.0f;
    for (int k = 0; k < 68; ++k) {
        const float xk = row[k];
        const float* w = w3_ws + k * 64;
#pragma unroll
        for (int o = 0; o < 64; ++o) acc[o] = fmaf(xk, w[o], acc[o]);
    }

    // ---- final epilogue: write payload (fire-and-forget stores)
    float* P = payload + (size_t)e * 76;
    float gp3[4] = {0.f, 0.f, 0.f, 0.f};
#pragma unroll
    for (int o = 0; o < 64; ++o) {
        const float s3 = acc[o] + w3_wsb[o];
#pragma unroll
        for (int vo = 0; vo < 4; ++vo) gp3[vo] = fmaf(s3, w3_wsv[o * 4 + vo], gp3[vo]);
        P[o] = s3;
        if (ovf) atomicAdd(&accS[(size_t)dst * 64 + o], s3);
    }
    float g3[4];
#pragma unroll
    for (int vo = 0; vo < 4; ++vo) g3[vo] = sigm(gp3[vo] + w3_wsvb[vo]);
#pragma unroll
    for (int vo = 0; vo < 4; ++vo)
#pragma unroll
        for (int d = 0; d < 3; ++d) {
            float t = 0.0f;
#pragma unroll
            for (int h = 0; h < 4; ++h) t = fmaf(vh3[d * 4 + h], w3_wv[h * 4 + vo], t);
            const float val = t * g3[vo];
            P[64 + vo * 3 + d] = val;
            if (ovf) atomicAdd(&accV[(size_t)dst * 12 + vo * 3 + d], val);
        }
}

// ================= node aggregate + finalize (one wave per node) =================
__global__ __launch_bounds__(256) void node_agg_kernel(
    const float* __restrict__ payload, const int* __restrict__ slotCnt,
    const int* __restrict__ slotTab, const float* __restrict__ accS,
    const float* __restrict__ accV, const int* __restrict__ mask,
    float* __restrict__ out, int N)
{
    const int gtid = blockIdx.x * 256 + threadIdx.x;
    const int n = gtid >> 6;
    const int lane = threadIdx.x & 63;
    if (n >= N) return;

    const int cnt = slotCnt[n];
    const int m = (cnt < 64) ? cnt : 64;

    int eid_l = (lane < m) ? slotTab[(size_t)n * 64 + lane] : 0;

    float ps[4] = {0.f, 0.f, 0.f, 0.f};
    float pvv[4] = {0.f, 0.f, 0.f, 0.f};
    for (int j = 0; j < m; j += 4) {
#pragma unroll
        for (int u = 0; u < 4; ++u) {
            const int jj = j + u;
            if (jj < m) {
                const int eid = __shfl(eid_l, jj, 64);
                const float* P = payload + (size_t)eid * 76;
                ps[u] += P[lane];
                if (lane < 12) pvv[u] += P[64 + lane];
            }
        }
    }
    float sS = (ps[0] + ps[1]) + (ps[2] + ps[3]);
    float sV = (pvv[0] + pvv[1]) + (pvv[2] + pvv[3]);
    sS += accS[(size_t)n * 64 + lane];
    if (lane < 12) sV += accV[(size_t)n * 12 + lane];

    const float denom = fmaxf((float)cnt, 1.0f);
    const float mk = (mask[n] != 0) ? 1.0f : 0.0f;

    const float s = sS / denom;
    const float r = (lane < 7) ? __cosf(s) : (lane < 14) ? __sinf(s) : __expf(s);
    out[(size_t)n * 64 + lane] = r * mk;

    const float vm = sV / denom;
    const int vo3 = (lane / 3) * 3;
    const float c0 = __shfl(vm, vo3 + 0, 64);
    const float c1 = __shfl(vm, vo3 + 1, 64);
    const float c2 = __shfl(vm, vo3 + 2, 64);
    if (lane < 12) {
        const float mag = sqrtf(c0 * c0 + c1 * c1 + c2 * c2);
        out[(size_t)N * 64 + (size_t)n * 12 + lane] = (vm / (mag + 1e-8f)) * mk;
    }
}

// ================= round-7 atomic edge kernel (fallback if ws too small) =================
__global__ __launch_bounds__(64) void gvp_edge_fast_kernel(
    const int* __restrict__ ei, const float* __restrict__ edge_s,
    const float* __restrict__ edge_v,
    const float* __restrict__ ysA, const float* __restrict__ ysB,
    const float* __restrict__ va, const float* __restrict__ vb,
    const float* __restrict__ w1_wh, const float* __restrict__ w1_ws,
    const float* __restrict__ w1_wsb, const float* __restrict__ w1_wv,
    const float* __restrict__ w1_wsv, const float* __restrict__ w1_wsvb,
    const float* __restrict__ w2_wh, const float* __restrict__ w2_ws,
    const float* __restrict__ w2_wsb, const float* __restrict__ w2_wv,
    const float* __restrict__ w2_wsv, const float* __restrict__ w2_wsvb,
    const float* __restrict__ w3_wh, const float* __restrict__ w3_ws,
    const float* __restrict__ w3_wsb, const float* __restrict__ w3_wv,
    const float* __restrict__ w3_wsv, const float* __restrict__ w3_wsvb,
    float* __restrict__ out_s, float* __restrict__ out_v,
    float* __restrict__ cnt, int E)
{
    __shared__ float rows[64 * 69];
    float* row = rows + threadIdx.x * 69;
    const int e = blockIdx.x * 64 + threadIdx.x;
    if (e >= E) return;
    const int src = ei[e];
    const int dst = ei[E + e];
    const float ev0 = edge_v[(size_t)e * 3 + 0];
    const float ev1 = edge_v[(size_t)e * 3 + 1];
    const float ev2 = edge_v[(size_t)e * 3 + 2];

    float acc[64];
#pragma unroll
    for (int o = 0; o < 64; ++o) acc[o] = 0.0f;
    float pv[12];
#pragma unroll
    for (int i = 0; i < 12; ++i) pv[i] = 0.0f;

    const float* vaP = va + (size_t)src * 100;
    const float* vbP = vb + (size_t)dst * 100;
    for (int g = 0; g < 8; ++g) {
        float ca[12];
        {
            float4 A0 = *(const float4*)(vaP + g * 12 + 0);
            float4 A1 = *(const float4*)(vaP + g * 12 + 4);
            float4 A2 = *(const float4*)(vaP + g * 12 + 8);
            float4 B0 = *(const float4*)(vbP + g * 12 + 0);
            float4 B1 = *(const float4*)(vbP + g * 12 + 4);
            float4 B2 = *(const float4*)(vbP + g * 12 + 8);
            ca[0] = A0.x + B0.x; ca[1] = A0.y + B0.y; ca[2]  = A0.z + B0.z; ca[3]  = A0.w + B0.w;
            ca[4] = A1.x + B1.x; ca[5] = A1.y + B1.y; ca[6]  = A1.z + B1.z; ca[7]  = A1.w + B1.w;
            ca[8] = A2.x + B2.x; ca[9] = A2.y + B2.y; ca[10] = A2.z + B2.z; ca[11] = A2.w + B2.w;
        }
        const float* weP = w1_wh + 16 * 33 + 4 * g;
        const float* wvP = w1_wv + (4 * g) * 4;
        const float* wsP = w1_ws + (size_t)(288 + 4 * g) * 64;
#pragma unroll
        for (int i = 0; i < 4; ++i) {
            const float we = weP[i];
            const float d0 = ca[3 * i + 0] + ev0 * we;
            const float d1 = ca[3 * i + 1] + ev1 * we;
            const float d2 = ca[3 * i + 2] + ev2 * we;
            const float vn = sqrtf(fmaxf(d0 * d0 + d1 * d1 + d2 * d2, 1e-8f));
            const float* wr = wsP + i * 64;
#pragma unroll
            for (int o = 0; o < 64; ++o) acc[o] = fmaf(vn, wr[o], acc[o]);
#pragma unroll
            for (int vo = 0; vo < 4; ++vo) {
                const float w = wvP[i * 4 + vo];
                pv[vo * 3 + 0] = fmaf(d0, w, pv[vo * 3 + 0]);
                pv[vo * 3 + 1] = fmaf(d1, w, pv[vo * 3 + 1]);
                pv[vo * 3 + 2] = fmaf(d2, w, pv[vo * 3 + 2]);
            }
        }
    }
    {
        float4 A = *(const float4*)(vaP + 96);
        float4 B = *(const float4*)(vbP + 96);
        const float we = w1_wh[16 * 33 + 32];
        const float d0 = A.x + B.x + ev0 * we;
        const float d1 = A.y + B.y + ev1 * we;
        const float d2 = A.z + B.z + ev2 * we;
        const float vn = sqrtf(fmaxf(d0 * d0 + d1 * d1 + d2 * d2, 1e-8f));
        const float* wr = w1_ws + (size_t)320 * 64;
#pragma unroll
        for (int o = 0; o < 64; ++o) acc[o] = fmaf(vn, wr[o], acc[o]);
#pragma unroll
        for (int vo = 0; vo < 4; ++vo) {
            const float w = w1_wv[32 * 4 + vo];
            pv[vo * 3 + 0] = fmaf(d0, w, pv[vo * 3 + 0]);
            pv[vo * 3 + 1] = fmaf(d1, w, pv[vo * 3 + 1]);
            pv[vo * 3 + 2] = fmaf(d2, w, pv[vo * 3 + 2]);
        }
    }
    {
        const float4* pa = (const float4*)(ysA + (size_t)src * 64);
        const float4* pb = (const float4*)(ysB + (size_t)dst * 64);
#pragma unroll
        for (int q = 0; q < 16; ++q) {
            float4 xa = pa[q], xb = pb[q];
            acc[4 * q + 0] += xa.x + xb.x;
            acc[4 * q + 1] += xa.y + xb.y;
            acc[4 * q + 2] += xa.z + xb.z;
            acc[4 * q + 3] += xa.w + xb.w;
        }
    }
    {
        const float4* xs = (const float4*)(edge_s + (size_t)e * 32);
        for (int k4 = 0; k4 < 8; ++k4) { float4 x = xs[k4]; RANK4(x, w1_ws + (size_t)(128 + k4 * 4) * 64); }
    }
    float gp[4] = {0.f, 0.f, 0.f, 0.f};
#pragma unroll
    for (int o = 0; o < 64; ++o) {
        const float s = acc[o] + w1_wsb[o];
        const float sg = sigm(s);
#pragma unroll
        for (int vo = 0; vo < 4; ++vo) gp[vo] = fmaf(sg, w1_wsv[o * 4 + vo], gp[vo]);
        row[o] = fmaxf(s, 0.0f);
    }
    float g1[4];
#pragma unroll
    for (int vo = 0; vo < 4; ++vo) g1[vo] = sigm(gp[vo] + w1_wsvb[vo]);
    float v1g[12];
#pragma unroll
    for (int vo = 0; vo < 4; ++vo)
#pragma unroll
        for (int d = 0; d < 3; ++d) v1g[vo * 3 + d] = pv[vo * 3 + d] * g1[vo];
    float vh2[12];
#pragma unroll
    for (int i = 0; i < 12; ++i) vh2[i] = 0.0f;
#pragma unroll
    for (int c = 0; c < 4; ++c)
#pragma unroll
        for (int h = 0; h < 4; ++h) {
            const float w = w2_wh[c * 4 + h];
#pragma unroll
            for (int d = 0; d < 3; ++d) vh2[d * 4 + h] = fmaf(v1g[c * 3 + d], w, vh2[d * 4 + h]);
        }
#pragma unroll
    for (int h = 0; h < 4; ++h) {
        const float ss = vh2[h] * vh2[h] + vh2[4 + h] * vh2[4 + h] + vh2[8 + h] * vh2[8 + h];
        row[64 + h] = sqrtf(fmaxf(ss, 1e-8f));
    }
    float acc2[64];
#pragma unroll
    for (int o = 0; o < 64; ++o) acc2[o] = 0.0f;
    for (int k = 0; k < 68; ++k) {
        const float xk = row[k];
        const float* w = w2_ws + k * 64;
#pragma unroll
        for (int o = 0; o < 64; ++o) acc2[o] = fmaf(xk, w[o], acc2[o]);
    }
    float gp2[4] = {0.f, 0.f, 0.f, 0.f};
#pragma unroll
    for (int o = 0; o < 64; ++o) {
        const float s = acc2[o] + w2_wsb[o];
        const float sg = sigm(s);
#pragma unroll
        for (int vo = 0; vo < 4; ++vo) gp2[vo] = fmaf(sg, w2_wsv[o * 4 + vo], gp2[vo]);
        row[o] = fmaxf(s, 0.0f);
    }
    float g2[4];
#pragma unroll
    for (int vo = 0; vo < 4; ++vo) g2[vo] = sigm(gp2[vo] + w2_wsvb[vo]);
    float v2g[12];
#pragma unroll
    for (int vo = 0; vo < 4; ++vo)
#pragma unroll
        for (int d = 0; d < 3; ++d) {
            float t = 0.0f;
#pragma unroll
            for (int h = 0; h < 4; ++h) t = fmaf(vh2[d * 4 + h], w2_wv[h * 4 + vo], t);
            v2g[vo * 3 + d] = t * g2[vo];
        }
    float vh3[12];
#pragma unroll
    for (int i = 0; i < 12; ++i) vh3[i] = 0.0f;
#pragma unroll
    for (int c = 0; c < 4; ++c)
#pragma unroll
        for (int h = 0; h < 4; ++h) {
            const float w = w3_wh[c * 4 + h];
#pragma unroll
            for (int d = 0; d < 3; ++d) vh3[d * 4 + h] = fmaf(v2g[c * 3 + d], w, vh3[d * 4 + h]);
        }
#pragma unroll
    for (int h = 0; h < 4; ++h) {
        const float ss = vh3[h] * vh3[h] + vh3[4 + h] * vh3[4 + h] + vh3[8 + h] * vh3[8 + h];
        row[64 + h] = sqrtf(fmaxf(ss, 1e-8f));
    }
#pragma unroll
    for (int o = 0; o < 64; ++o) acc[o] = 0.0f;
    for (int k = 0; k < 68; ++k) {
        const float xk = row[k];
        const float* w = w3_ws + k * 64;
#pragma unroll
        for (int o = 0; o < 64; ++o) acc[o] = fmaf(xk, w[o], acc[o]);
    }
    float gp3[4] = {0.f, 0.f, 0.f, 0.f};
#pragma unroll
    for (int o = 0; o < 64; ++o) {
        const float s3 = acc[o] + w3_wsb[o];
#pragma unroll
        for (int vo = 0; vo < 4; ++vo) gp3[vo] = fmaf(s3, w3_wsv[o * 4 + vo], gp3[vo]);
        atomicAdd(&out_s[(size_t)dst * 64 + o], s3);
    }
    float g3[4];
#pragma unroll
    for (int vo = 0; vo < 4; ++vo) g3[vo] = sigm(gp3[vo] + w3_wsvb[vo]);
#pragma unroll
    for (int vo = 0; vo < 4; ++vo)
#pragma unroll
        for (int d = 0; d < 3; ++d) {
            float t = 0.0f;
#pragma unroll
            for (int h = 0; h < 4; ++h) t = fmaf(vh3[d * 4 + h], w3_wv[h * 4 + vo], t);
            atomicAdd(&out_v[(size_t)dst * 12 + vo * 3 + d], t * g3[vo]);
        }
    atomicAdd(&cnt[dst], 1.0f);
}

// ================= finalize (fallback path only) =================
__global__ void gvp_finalize_kernel(float* __restrict__ out,
                                    const float* __restrict__ cnt,
                                    const int* __restrict__ mask, int N)
{
    const int g = blockIdx.x * blockDim.x + threadIdx.x;
    const int ns = N * 64;
    const int total = ns + N * 4;
    if (g >= total) return;
    if (g < ns) {
        const int n = g >> 6, j = g & 63;
        const float denom = fmaxf(cnt[n], 1.0f);
        const float m = (mask[n] != 0) ? 1.0f : 0.0f;
        const float s = out[g] / denom;
        const float r = (j < 7) ? __cosf(s) : (j < 14) ? __sinf(s) : __expf(s);
        out[g] = r * m;
    } else {
        const int g2 = g - ns;
        const int n = g2 >> 2, vo = g2 & 3;
        const float denom = fmaxf(cnt[n], 1.0f);
        const float m = (mask[n] != 0) ? 1.0f : 0.0f;
        float* vp = out + ns + (size_t)n * 12 + vo * 3;
        const float v0 = vp[0] / denom, v1 = vp[1] / denom, v2 = vp[2] / denom;
        const float mag = sqrtf(v0 * v0 + v1 * v1 + v2 * v2);
        const float inv = m / (mag + 1e-8f);
        vp[0] = v0 * inv; vp[1] = v1 * inv; vp[2] = v2 * inv;
    }
}

extern "C" void kernel_launch(void* const* d_in, const int* in_sizes, int n_in,
                              void* d_out, int out_size, void* d_ws, size_t ws_size,
                              hipStream_t stream)
{
    const float* node_s = (const float*)d_in[0];
    const float* node_v = (const float*)d_in[1];
    const int*   ei     = (const int*)d_in[2];
    const float* edge_s = (const float*)d_in[3];
    const float* edge_v = (const float*)d_in[4];
    const int*   mask   = (const int*)d_in[5];
    const float* w1_wh  = (const float*)d_in[6];
    const float* w1_ws  = (const float*)d_in[7];
    const float* w1_wsb = (const float*)d_in[8];
    const float* w1_wv  = (const float*)d_in[9];
    const float* w1_wsv = (const float*)d_in[10];
    const float* w1_wsvb= (const float*)d_in[11];
    const float* w2_wh  = (const float*)d_in[12];
    const float* w2_ws  = (const float*)d_in[13];
    const float* w2_wsb = (const float*)d_in[14];
    const float* w2_wv  = (const float*)d_in[15];
    const float* w2_wsv = (const float*)d_in[16];
    const float* w2_wsvb= (const float*)d_in[17];
    const float* w3_wh  = (const float*)d_in[18];
    const float* w3_ws  = (const float*)d_in[19];
    const float* w3_wsb = (const float*)d_in[20];
    const float* w3_wv  = (const float*)d_in[21];
    const float* w3_wsv = (const float*)d_in[22];
    const float* w3_wsvb= (const float*)d_in[23];

    const int N = in_sizes[0] / 128;   // 20000
    const int E = in_sizes[3] / 32;    // 320000

    float* out = (float*)d_out;
    float* ws  = (float*)d_ws;

    // ws layout (floats): ysA N*64 | ysB N*64 | va N*100 | vb N*100 |
    //                     slotCnt N | slotTab N*64 | accS N*64 | accV N*12 | payload E*76
    const size_t oYA = 0;
    const size_t oYB = (size_t)N * 64;
    const size_t oVA = oYB + (size_t)N * 64;
    const size_t oVB = oVA + (size_t)N * 100;
    const size_t oSC = oVB + (size_t)N * 100;
    const size_t oST = oSC + (size_t)N;
    const size_t oAS = oST + (size_t)N * 64;
    const size_t oAV = oAS + (size_t)N * 64;
    const size_t oPL = oAV + (size_t)N * 12;
    const size_t needF2 = oPL + (size_t)E * 76;              // ~134.8 MB
    const size_t needF1 = oSC + (size_t)N;                   // round-7 path (~26.3 MB)

    const bool fast2 = (ws_size >= needF2 * sizeof(float));
    const bool fast1 = (ws_size >= needF1 * sizeof(float));

    if (fast2) {
        int* slotCnt = (int*)(ws + oSC);
        int* slotTab = (int*)(ws + oST);
        float* accS = ws + oAS;
        float* accV = ws + oAV;
        float* payload = ws + oPL;

        hipMemsetAsync(slotCnt, 0, (size_t)N * sizeof(int), stream);
        hipMemsetAsync(accS, 0, (size_t)N * 76 * sizeof(float), stream);  // accS+accV contiguous

        node_pre_kernel<<<(N + 63) / 64, 64, 0, stream>>>(
            node_s, node_v, w1_wh, w1_ws,
            ws + oYA, ws + oYB, ws + oVA, ws + oVB, N);
        gvp_edge_scatter_kernel<<<(E + 63) / 64, 64, 0, stream>>>(
            ei, edge_s, edge_v,
            ws + oYA, ws + oYB, ws + oVA, ws + oVB,
            w1_wh, w1_ws, w1_wsb, w1_wv, w1_wsv, w1_wsvb,
            w2_wh, w2_ws, w2_wsb, w2_wv, w2_wsv, w2_wsvb,
            w3_wh, w3_ws, w3_wsb, w3_wv, w3_wsv, w3_wsvb,
            payload, slotCnt, slotTab, accS, accV, E);
        node_agg_kernel<<<(N * 64 + 255) / 256, 256, 0, stream>>>(
            payload, slotCnt, slotTab, accS, accV, mask, out, N);
    } else if (fast1) {
        float* cnt = ws + oSC;
        hipMemsetAsync(d_out, 0, (size_t)out_size * sizeof(float), stream);
        hipMemsetAsync(cnt, 0, (size_t)N * sizeof(float), stream);
        node_pre_kernel<<<(N + 63) / 64, 64, 0, stream>>>(
            node_s, node_v, w1_wh, w1_ws,
            ws + oYA, ws + oYB, ws + oVA, ws + oVB, N);
        gvp_edge_fast_kernel<<<(E + 63) / 64, 64, 0, stream>>>(
            ei, edge_s, edge_v,
            ws + oYA, ws + oYB, ws + oVA, ws + oVB,
            w1_wh, w1_ws, w1_wsb, w1_wv, w1_wsv, w1_wsvb,
            w2_wh, w2_ws, w2_wsb, w2_wv, w2_wsv, w2_wsvb,
            w3_wh, w3_ws, w3_wsb, w3_wv, w3_wsv, w3_wsvb,
            out, out + (size_t)N * 64, cnt, E);
        const int total2 = N * 68;
        gvp_finalize_kernel<<<(total2 + 255) / 256, 256, 0, stream>>>(out, cnt, mask, N);
    }
}

// Round 10
// 521.171 us; speedup vs baseline: 3.2386x; 1.3260x over previous
//
#include <hip/hip_runtime.h>
#include <hip/hip_fp16.h>
#include <math.h>

__device__ __forceinline__ float sigm(float x) { return 1.0f / (1.0f + __expf(-x)); }

// rank-4 update of acc[64] from one float4 of x and 4 weight rows (uniform addr)
#define RANK4(XV, WPTR) do {                                                            \
    const float* w_ = (WPTR);                                                           \
    _Pragma("unroll") for (int o_ = 0; o_ < 64; ++o_) acc[o_] = fmaf((XV).x, w_[o_],       acc[o_]); \
    _Pragma("unroll") for (int o_ = 0; o_ < 64; ++o_) acc[o_] = fmaf((XV).y, w_[64 + o_],  acc[o_]); \
    _Pragma("unroll") for (int o_ = 0; o_ < 64; ++o_) acc[o_] = fmaf((XV).z, w_[128 + o_], acc[o_]); \
    _Pragma("unroll") for (int o_ = 0; o_ < 64; ++o_) acc[o_] = fmaf((XV).w, w_[192 + o_], acc[o_]); \
} while (0)

// ================= node precompute: 4-way split (oq = block-uniform quadrant) =================
// oq computes: scalar outputs [oq*16, oq*16+16) of ysA/ysB; vh columns h in [h0,h0+hn)
__global__ __launch_bounds__(64) void node_pre_kernel(
    const float* __restrict__ node_s, const float* __restrict__ node_v,
    const float* __restrict__ w1_wh, const float* __restrict__ w1_ws,
    float* __restrict__ ysA, float* __restrict__ ysB,
    float* __restrict__ va, float* __restrict__ vb, int N)
{
    const int oq = blockIdx.x & 3;                 // block-uniform
    const int n  = (blockIdx.x >> 2) * 64 + threadIdx.x;
    if (n >= N) return;

    // ---- vector part (this quadrant's h range)
    float v[48];
    {
        const float4* vs = (const float4*)(node_v + (size_t)n * 48);
#pragma unroll
        for (int j = 0; j < 12; ++j) {
            float4 t = vs[j];
            v[4 * j + 0] = t.x; v[4 * j + 1] = t.y; v[4 * j + 2] = t.z; v[4 * j + 3] = t.w;
        }
    }
    const int h0 = (oq == 0) ? 0 : (1 + oq * 8);   // 0,9,17,25
    const int hn = (oq == 0) ? 9 : 8;
    float* vaP = va + (size_t)n * 100;
    float* vbP = vb + (size_t)n * 100;
    for (int hh = 0; hh < hn; ++hh) {
        const int h = h0 + hh;                     // block-uniform
        const float* wc = w1_wh + h;
        float a0 = 0.f, a1 = 0.f, a2 = 0.f, b0 = 0.f, b1 = 0.f, b2 = 0.f;
#pragma unroll
        for (int c = 0; c < 16; ++c) {
            const float wa = wc[c * 33];
            const float wb = wc[(17 + c) * 33];
            a0 = fmaf(v[3 * c + 0], wa, a0); a1 = fmaf(v[3 * c + 1], wa, a1); a2 = fmaf(v[3 * c + 2], wa, a2);
            b0 = fmaf(v[3 * c + 0], wb, b0); b1 = fmaf(v[3 * c + 1], wb, b1); b2 = fmaf(v[3 * c + 2], wb, b2);
        }
        vaP[3 * h + 0] = a0; vaP[3 * h + 1] = a1; vaP[3 * h + 2] = a2;
        vbP[3 * h + 0] = b0; vbP[3 * h + 1] = b1; vbP[3 * h + 2] = b2;
    }

    // ---- scalar part: 16 outputs, both roles, x loaded once
    const float4* xs = (const float4*)(node_s + (size_t)n * 128);
    float aA[16], aB[16];
#pragma unroll
    for (int j = 0; j < 16; ++j) { aA[j] = 0.0f; aB[j] = 0.0f; }
    for (int k4 = 0; k4 < 32; ++k4) {
        float4 x = xs[k4];
        float xc[4] = {x.x, x.y, x.z, x.w};
        const float* wA = w1_ws + (size_t)(k4 * 4) * 64 + oq * 16;          // uniform
        const float* wB = w1_ws + (size_t)(160 + k4 * 4) * 64 + oq * 16;    // uniform
#pragma unroll
        for (int r = 0; r < 4; ++r) {
#pragma unroll
            for (int j = 0; j < 16; ++j) {
                aA[j] = fmaf(xc[r], wA[r * 64 + j], aA[j]);
                aB[j] = fmaf(xc[r], wB[r * 64 + j], aB[j]);
            }
        }
    }
    {
        float4* oa = (float4*)(ysA + (size_t)n * 64 + oq * 16);
        float4* ob = (float4*)(ysB + (size_t)n * 64 + oq * 16);
#pragma unroll
        for (int q = 0; q < 4; ++q) {
            float4 t; t.x = aA[4*q]; t.y = aA[4*q+1]; t.z = aA[4*q+2]; t.w = aA[4*q+3]; oa[q] = t;
            float4 u; u.x = aB[4*q]; u.y = aB[4*q+1]; u.z = aB[4*q+2]; u.w = aB[4*q+3]; ob[q] = u;
        }
    }
}

// ================= edge kernel: scatter results, 1 atomic/edge, fp16 LDS row =================
__global__ __launch_bounds__(64) void gvp_edge_scatter_kernel(
    const int* __restrict__ ei, const float* __restrict__ edge_s,
    const float* __restrict__ edge_v,
    const float* __restrict__ ysA, const float* __restrict__ ysB,
    const float* __restrict__ va, const float* __restrict__ vb,
    const float* __restrict__ w1_wh, const float* __restrict__ w1_ws,
    const float* __restrict__ w1_wsb, const float* __restrict__ w1_wv,
    const float* __restrict__ w1_wsv, const float* __restrict__ w1_wsvb,
    const float* __restrict__ w2_wh, const float* __restrict__ w2_ws,
    const float* __restrict__ w2_wsb, const float* __restrict__ w2_wv,
    const float* __restrict__ w2_wsv, const float* __restrict__ w2_wsvb,
    const float* __restrict__ w3_wh, const float* __restrict__ w3_ws,
    const float* __restrict__ w3_wsb, const float* __restrict__ w3_wv,
    const float* __restrict__ w3_wsv, const float* __restrict__ w3_wsvb,
    float* __restrict__ payload, int* __restrict__ slotCnt,
    int* __restrict__ slotTab, float* __restrict__ accS,
    float* __restrict__ accV, int E)
{
    __shared__ __half rows[64 * 70];          // 8.96 KB/block -> ~16 waves/CU cap
    __half* row = rows + threadIdx.x * 70;    // stride 70 halves = 35 dwords (odd) -> bank-spread
    const int e = blockIdx.x * 64 + threadIdx.x;
    if (e >= E) return;
    const int src = ei[e];
    const int dst = ei[E + e];

    // slot reservation early: RMW latency hides under compute below
    const int slot = atomicAdd(&slotCnt[dst], 1);
    if (slot < 64) slotTab[(size_t)dst * 64 + slot] = e;
    const bool ovf = (slot >= 64);

    const float ev0 = edge_v[(size_t)e * 3 + 0];
    const float ev1 = edge_v[(size_t)e * 3 + 1];
    const float ev2 = edge_v[(size_t)e * 3 + 2];

    float acc[64];
#pragma unroll
    for (int o = 0; o < 64; ++o) acc[o] = 0.0f;
    float pv[12];
#pragma unroll
    for (int i = 0; i < 12; ++i) pv[i] = 0.0f;

    const float* vaP = va + (size_t)src * 100;
    const float* vbP = vb + (size_t)dst * 100;
    for (int g = 0; g < 8; ++g) {
        float ca[12];
        {
            float4 A0 = *(const float4*)(vaP + g * 12 + 0);
            float4 A1 = *(const float4*)(vaP + g * 12 + 4);
            float4 A2 = *(const float4*)(vaP + g * 12 + 8);
            float4 B0 = *(const float4*)(vbP + g * 12 + 0);
            float4 B1 = *(const float4*)(vbP + g * 12 + 4);
            float4 B2 = *(const float4*)(vbP + g * 12 + 8);
            ca[0] = A0.x + B0.x; ca[1] = A0.y + B0.y; ca[2]  = A0.z + B0.z; ca[3]  = A0.w + B0.w;
            ca[4] = A1.x + B1.x; ca[5] = A1.y + B1.y; ca[6]  = A1.z + B1.z; ca[7]  = A1.w + B1.w;
            ca[8] = A2.x + B2.x; ca[9] = A2.y + B2.y; ca[10] = A2.z + B2.z; ca[11] = A2.w + B2.w;
        }
        const float* weP = w1_wh + 16 * 33 + 4 * g;
        const float* wvP = w1_wv + (4 * g) * 4;
        const float* wsP = w1_ws + (size_t)(288 + 4 * g) * 64;
#pragma unroll
        for (int i = 0; i < 4; ++i) {
            const float we = weP[i];
            const float d0 = ca[3 * i + 0] + ev0 * we;
            const float d1 = ca[3 * i + 1] + ev1 * we;
            const float d2 = ca[3 * i + 2] + ev2 * we;
            const float vn = sqrtf(fmaxf(d0 * d0 + d1 * d1 + d2 * d2, 1e-8f));
            const float* wr = wsP + i * 64;
#pragma unroll
            for (int o = 0; o < 64; ++o) acc[o] = fmaf(vn, wr[o], acc[o]);
#pragma unroll
            for (int vo = 0; vo < 4; ++vo) {
                const float w = wvP[i * 4 + vo];
                pv[vo * 3 + 0] = fmaf(d0, w, pv[vo * 3 + 0]);
                pv[vo * 3 + 1] = fmaf(d1, w, pv[vo * 3 + 1]);
                pv[vo * 3 + 2] = fmaf(d2, w, pv[vo * 3 + 2]);
            }
        }
    }
    {   // tail h = 32
        float4 A = *(const float4*)(vaP + 96);
        float4 B = *(const float4*)(vbP + 96);
        const float we = w1_wh[16 * 33 + 32];
        const float d0 = A.x + B.x + ev0 * we;
        const float d1 = A.y + B.y + ev1 * we;
        const float d2 = A.z + B.z + ev2 * we;
        const float vn = sqrtf(fmaxf(d0 * d0 + d1 * d1 + d2 * d2, 1e-8f));
        const float* wr = w1_ws + (size_t)320 * 64;
#pragma unroll
        for (int o = 0; o < 64; ++o) acc[o] = fmaf(vn, wr[o], acc[o]);
#pragma unroll
        for (int vo = 0; vo < 4; ++vo) {
            const float w = w1_wv[32 * 4 + vo];
            pv[vo * 3 + 0] = fmaf(d0, w, pv[vo * 3 + 0]);
            pv[vo * 3 + 1] = fmaf(d1, w, pv[vo * 3 + 1]);
            pv[vo * 3 + 2] = fmaf(d2, w, pv[vo * 3 + 2]);
        }
    }

    {
        const float4* pa = (const float4*)(ysA + (size_t)src * 64);
        const float4* pb = (const float4*)(ysB + (size_t)dst * 64);
#pragma unroll
        for (int q = 0; q < 16; ++q) {
            float4 xa = pa[q], xb = pb[q];
            acc[4 * q + 0] += xa.x + xb.x;
            acc[4 * q + 1] += xa.y + xb.y;
            acc[4 * q + 2] += xa.z + xb.z;
            acc[4 * q + 3] += xa.w + xb.w;
        }
    }
    {
        const float4* xs = (const float4*)(edge_s + (size_t)e * 32);
        for (int k4 = 0; k4 < 8; ++k4) { float4 x = xs[k4]; RANK4(x, w1_ws + (size_t)(128 + k4 * 4) * 64); }
    }

    // ---- layer-1 epilogue (row -> fp16 LDS)
    float gp[4] = {0.f, 0.f, 0.f, 0.f};
#pragma unroll
    for (int o = 0; o < 64; ++o) {
        const float s = acc[o] + w1_wsb[o];
        const float sg = sigm(s);
#pragma unroll
        for (int vo = 0; vo < 4; ++vo) gp[vo] = fmaf(sg, w1_wsv[o * 4 + vo], gp[vo]);
        row[o] = __float2half(fmaxf(s, 0.0f));
    }
    float g1[4];
#pragma unroll
    for (int vo = 0; vo < 4; ++vo) g1[vo] = sigm(gp[vo] + w1_wsvb[vo]);
    float v1g[12];
#pragma unroll
    for (int vo = 0; vo < 4; ++vo)
#pragma unroll
        for (int d = 0; d < 3; ++d) v1g[vo * 3 + d] = pv[vo * 3 + d] * g1[vo];
    float vh2[12];
#pragma unroll
    for (int i = 0; i < 12; ++i) vh2[i] = 0.0f;
#pragma unroll
    for (int c = 0; c < 4; ++c)
#pragma unroll
        for (int h = 0; h < 4; ++h) {
            const float w = w2_wh[c * 4 + h];
#pragma unroll
            for (int d = 0; d < 3; ++d) vh2[d * 4 + h] = fmaf(v1g[c * 3 + d], w, vh2[d * 4 + h]);
        }
#pragma unroll
    for (int h = 0; h < 4; ++h) {
        const float ss = vh2[h] * vh2[h] + vh2[4 + h] * vh2[4 + h] + vh2[8 + h] * vh2[8 + h];
        row[64 + h] = __float2half(sqrtf(fmaxf(ss, 1e-8f)));
    }

    // ---- GEMM2
    float acc2[64];
#pragma unroll
    for (int o = 0; o < 64; ++o) acc2[o] = 0.0f;
    for (int k = 0; k < 68; ++k) {
        const float xk = __half2float(row[k]);
        const float* w = w2_ws + k * 64;
#pragma unroll
        for (int o = 0; o < 64; ++o) acc2[o] = fmaf(xk, w[o], acc2[o]);
    }

    // ---- layer-2 epilogue
    float gp2[4] = {0.f, 0.f, 0.f, 0.f};
#pragma unroll
    for (int o = 0; o < 64; ++o) {
        const float s = acc2[o] + w2_wsb[o];
        const float sg = sigm(s);
#pragma unroll
        for (int vo = 0; vo < 4; ++vo) gp2[vo] = fmaf(sg, w2_wsv[o * 4 + vo], gp2[vo]);
        row[o] = __float2half(fmaxf(s, 0.0f));
    }
    float g2[4];
#pragma unroll
    for (int vo = 0; vo < 4; ++vo) g2[vo] = sigm(gp2[vo] + w2_wsvb[vo]);
    float v2g[12];
#pragma unroll
    for (int vo = 0; vo < 4; ++vo)
#pragma unroll
        for (int d = 0; d < 3; ++d) {
            float t = 0.0f;
#pragma unroll
            for (int h = 0; h < 4; ++h) t = fmaf(vh2[d * 4 + h], w2_wv[h * 4 + vo], t);
            v2g[vo * 3 + d] = t * g2[vo];
        }
    float vh3[12];
#pragma unroll
    for (int i = 0; i < 12; ++i) vh3[i] = 0.0f;
#pragma unroll
    for (int c = 0; c < 4; ++c)
#pragma unroll
        for (int h = 0; h < 4; ++h) {
            const float w = w3_wh[c * 4 + h];
#pragma unroll
            for (int d = 0; d < 3; ++d) vh3[d * 4 + h] = fmaf(v2g[c * 3 + d], w, vh3[d * 4 + h]);
        }
#pragma unroll
    for (int h = 0; h < 4; ++h) {
        const float ss = vh3[h] * vh3[h] + vh3[4 + h] * vh3[4 + h] + vh3[8 + h] * vh3[8 + h];
        row[64 + h] = __float2half(sqrtf(fmaxf(ss, 1e-8f)));
    }

    // ---- GEMM3
#pragma unroll
    for (int o = 0; o < 64; ++o) acc[o] = 0.0f;
    for (int k = 0; k < 68; ++k) {
        const float xk = __half2float(row[k]);
        const float* w = w3_ws + k * 64;
#pragma unroll
        for (int o = 0; o < 64; ++o) acc[o] = fmaf(xk, w[o], acc[o]);
    }

    // ---- final epilogue: write payload (fire-and-forget stores)
    float* P = payload + (size_t)e * 76;
    float gp3[4] = {0.f, 0.f, 0.f, 0.f};
#pragma unroll
    for (int o = 0; o < 64; ++o) {
        const float s3 = acc[o] + w3_wsb[o];
#pragma unroll
        for (int vo = 0; vo < 4; ++vo) gp3[vo] = fmaf(s3, w3_wsv[o * 4 + vo], gp3[vo]);
        P[o] = s3;
        if (ovf) atomicAdd(&accS[(size_t)dst * 64 + o], s3);
    }
    float g3[4];
#pragma unroll
    for (int vo = 0; vo < 4; ++vo) g3[vo] = sigm(gp3[vo] + w3_wsvb[vo]);
#pragma unroll
    for (int vo = 0; vo < 4; ++vo)
#pragma unroll
        for (int d = 0; d < 3; ++d) {
            float t = 0.0f;
#pragma unroll
            for (int h = 0; h < 4; ++h) t = fmaf(vh3[d * 4 + h], w3_wv[h * 4 + vo], t);
            const float val = t * g3[vo];
            P[64 + vo * 3 + d] = val;
            if (ovf) atomicAdd(&accV[(size_t)dst * 12 + vo * 3 + d], val);
        }
}

// ================= node aggregate + finalize (one wave per node) =================
__global__ __launch_bounds__(256) void node_agg_kernel(
    const float* __restrict__ payload, const int* __restrict__ slotCnt,
    const int* __restrict__ slotTab, const float* __restrict__ accS,
    const float* __restrict__ accV, const int* __restrict__ mask,
    float* __restrict__ out, int N)
{
    const int gtid = blockIdx.x * 256 + threadIdx.x;
    const int n = gtid >> 6;
    const int lane = threadIdx.x & 63;
    if (n >= N) return;

    const int cnt = slotCnt[n];
    const int m = (cnt < 64) ? cnt : 64;

    int eid_l = (lane < m) ? slotTab[(size_t)n * 64 + lane] : 0;

    float ps[4] = {0.f, 0.f, 0.f, 0.f};
    float pvv[4] = {0.f, 0.f, 0.f, 0.f};
    for (int j = 0; j < m; j += 4) {
#pragma unroll
        for (int u = 0; u < 4; ++u) {
            const int jj = j + u;
            if (jj < m) {
                const int eid = __shfl(eid_l, jj, 64);
                const float* P = payload + (size_t)eid * 76;
                ps[u] += P[lane];
                if (lane < 12) pvv[u] += P[64 + lane];
            }
        }
    }
    float sS = (ps[0] + ps[1]) + (ps[2] + ps[3]);
    float sV = (pvv[0] + pvv[1]) + (pvv[2] + pvv[3]);
    sS += accS[(size_t)n * 64 + lane];
    if (lane < 12) sV += accV[(size_t)n * 12 + lane];

    const float denom = fmaxf((float)cnt, 1.0f);
    const float mk = (mask[n] != 0) ? 1.0f : 0.0f;

    const float s = sS / denom;
    const float r = (lane < 7) ? __cosf(s) : (lane < 14) ? __sinf(s) : __expf(s);
    out[(size_t)n * 64 + lane] = r * mk;

    const float vm = sV / denom;
    const int vo3 = (lane / 3) * 3;
    const float c0 = __shfl(vm, vo3 + 0, 64);
    const float c1 = __shfl(vm, vo3 + 1, 64);
    const float c2 = __shfl(vm, vo3 + 2, 64);
    if (lane < 12) {
        const float mag = sqrtf(c0 * c0 + c1 * c1 + c2 * c2);
        out[(size_t)N * 64 + (size_t)n * 12 + lane] = (vm / (mag + 1e-8f)) * mk;
    }
}

extern "C" void kernel_launch(void* const* d_in, const int* in_sizes, int n_in,
                              void* d_out, int out_size, void* d_ws, size_t ws_size,
                              hipStream_t stream)
{
    const float* node_s = (const float*)d_in[0];
    const float* node_v = (const float*)d_in[1];
    const int*   ei     = (const int*)d_in[2];
    const float* edge_s = (const float*)d_in[3];
    const float* edge_v = (const float*)d_in[4];
    const int*   mask   = (const int*)d_in[5];
    const float* w1_wh  = (const float*)d_in[6];
    const float* w1_ws  = (const float*)d_in[7];
    const float* w1_wsb = (const float*)d_in[8];
    const float* w1_wv  = (const float*)d_in[9];
    const float* w1_wsv = (const float*)d_in[10];
    const float* w1_wsvb= (const float*)d_in[11];
    const float* w2_wh  = (const float*)d_in[12];
    const float* w2_ws  = (const float*)d_in[13];
    const float* w2_wsb = (const float*)d_in[14];
    const float* w2_wv  = (const float*)d_in[15];
    const float* w2_wsv = (const float*)d_in[16];
    const float* w2_wsvb= (const float*)d_in[17];
    const float* w3_wh  = (const float*)d_in[18];
    const float* w3_ws  = (const float*)d_in[19];
    const float* w3_wsb = (const float*)d_in[20];
    const float* w3_wv  = (const float*)d_in[21];
    const float* w3_wsv = (const float*)d_in[22];
    const float* w3_wsvb= (const float*)d_in[23];

    const int N = in_sizes[0] / 128;   // 20000
    const int E = in_sizes[3] / 32;    // 320000

    float* out = (float*)d_out;
    float* ws  = (float*)d_ws;

    // ws layout (floats): ysA N*64 | ysB N*64 | va N*100 | vb N*100 |
    //                     slotCnt N | slotTab N*64 | accS N*64 | accV N*12 | payload E*76
    const size_t oYA = 0;
    const size_t oYB = (size_t)N * 64;
    const size_t oVA = oYB + (size_t)N * 64;
    const size_t oVB = oVA + (size_t)N * 100;
    const size_t oSC = oVB + (size_t)N * 100;
    const size_t oST = oSC + (size_t)N;
    const size_t oAS = oST + (size_t)N * 64;
    const size_t oAV = oAS + (size_t)N * 64;
    const size_t oPL = oAV + (size_t)N * 12;
    const size_t needF2 = oPL + (size_t)E * 76;              // ~134.8 MB

    if (ws_size >= needF2 * sizeof(float)) {
        int* slotCnt = (int*)(ws + oSC);
        int* slotTab = (int*)(ws + oST);
        float* accS = ws + oAS;
        float* accV = ws + oAV;
        float* payload = ws + oPL;

        hipMemsetAsync(slotCnt, 0, (size_t)N * sizeof(int), stream);
        hipMemsetAsync(accS, 0, (size_t)N * 76 * sizeof(float), stream);  // accS+accV contiguous

        node_pre_kernel<<<((N + 63) / 64) * 4, 64, 0, stream>>>(
            node_s, node_v, w1_wh, w1_ws,
            ws + oYA, ws + oYB, ws + oVA, ws + oVB, N);
        gvp_edge_scatter_kernel<<<(E + 63) / 64, 64, 0, stream>>>(
            ei, edge_s, edge_v,
            ws + oYA, ws + oYB, ws + oVA, ws + oVB,
            w1_wh, w1_ws, w1_wsb, w1_wv, w1_wsv, w1_wsvb,
            w2_wh, w2_ws, w2_wsb, w2_wv, w2_wsv, w2_wsvb,
            w3_wh, w3_ws, w3_wsb, w3_wv, w3_wsv, w3_wsvb,
            payload, slotCnt, slotTab, accS, accV, E);
        node_agg_kernel<<<(N * 64 + 255) / 256, 256, 0, stream>>>(
            payload, slotCnt, slotTab, accS, accV, mask, out, N);
    }
}

// Round 11
// 520.640 us; speedup vs baseline: 3.2420x; 1.0010x over previous
//
#include <hip/hip_runtime.h>
#include <hip/hip_fp16.h>
#include <math.h>

__device__ __forceinline__ float sigm(float x) { return 1.0f / (1.0f + __expf(-x)); }

#define RANK4(XV, WPTR) do {                                                            \
    const float* w_ = (WPTR);                                                           \
    _Pragma("unroll") for (int o_ = 0; o_ < 64; ++o_) acc[o_] = fmaf((XV).x, w_[o_],       acc[o_]); \
    _Pragma("unroll") for (int o_ = 0; o_ < 64; ++o_) acc[o_] = fmaf((XV).y, w_[64 + o_],  acc[o_]); \
    _Pragma("unroll") for (int o_ = 0; o_ < 64; ++o_) acc[o_] = fmaf((XV).z, w_[128 + o_], acc[o_]); \
    _Pragma("unroll") for (int o_ = 0; o_ < 64; ++o_) acc[o_] = fmaf((XV).w, w_[192 + o_], acc[o_]); \
} while (0)

// ================= node precompute: 4-way split, fp16 table outputs =================
// vaH/vbH layout: [n][d][36] halves (stride 108/node); ysAH/ysBH: [n][64] halves.
__global__ __launch_bounds__(64) void node_pre_kernel(
    const float* __restrict__ node_s, const float* __restrict__ node_v,
    const float* __restrict__ w1_wh, const float* __restrict__ w1_ws,
    __half* __restrict__ ysA, __half* __restrict__ ysB,
    __half* __restrict__ va, __half* __restrict__ vb, int N)
{
    const int oq = blockIdx.x & 3;                 // block-uniform
    const int n  = (blockIdx.x >> 2) * 64 + threadIdx.x;
    if (n >= N) return;

    float v[48];
    {
        const float4* vs = (const float4*)(node_v + (size_t)n * 48);
#pragma unroll
        for (int j = 0; j < 12; ++j) {
            float4 t = vs[j];
            v[4 * j + 0] = t.x; v[4 * j + 1] = t.y; v[4 * j + 2] = t.z; v[4 * j + 3] = t.w;
        }
    }
    const int h0 = (oq == 0) ? 0 : (1 + oq * 8);   // 0,9,17,25
    const int hn = (oq == 0) ? 9 : 8;
    __half* vaP = va + (size_t)n * 108;
    __half* vbP = vb + (size_t)n * 108;
    for (int hh = 0; hh < hn; ++hh) {
        const int h = h0 + hh;                     // block-uniform
        const float* wc = w1_wh + h;
        float a0 = 0.f, a1 = 0.f, a2 = 0.f, b0 = 0.f, b1 = 0.f, b2 = 0.f;
#pragma unroll
        for (int c = 0; c < 16; ++c) {
            const float wa = wc[c * 33];
            const float wb = wc[(17 + c) * 33];
            a0 = fmaf(v[3 * c + 0], wa, a0); a1 = fmaf(v[3 * c + 1], wa, a1); a2 = fmaf(v[3 * c + 2], wa, a2);
            b0 = fmaf(v[3 * c + 0], wb, b0); b1 = fmaf(v[3 * c + 1], wb, b1); b2 = fmaf(v[3 * c + 2], wb, b2);
        }
        vaP[0 * 36 + h] = __float2half(a0); vaP[1 * 36 + h] = __float2half(a1); vaP[2 * 36 + h] = __float2half(a2);
        vbP[0 * 36 + h] = __float2half(b0); vbP[1 * 36 + h] = __float2half(b1); vbP[2 * 36 + h] = __float2half(b2);
    }

    // ---- scalar part: 16 outputs, both roles
    const float4* xs = (const float4*)(node_s + (size_t)n * 128);
    float aA[16], aB[16];
#pragma unroll
    for (int j = 0; j < 16; ++j) { aA[j] = 0.0f; aB[j] = 0.0f; }
    for (int k4 = 0; k4 < 32; ++k4) {
        float4 x = xs[k4];
        float xc[4] = {x.x, x.y, x.z, x.w};
        const float* wA = w1_ws + (size_t)(k4 * 4) * 64 + oq * 16;          // uniform
        const float* wB = w1_ws + (size_t)(160 + k4 * 4) * 64 + oq * 16;    // uniform
#pragma unroll
        for (int r = 0; r < 4; ++r) {
#pragma unroll
            for (int j = 0; j < 16; ++j) {
                aA[j] = fmaf(xc[r], wA[r * 64 + j], aA[j]);
                aB[j] = fmaf(xc[r], wB[r * 64 + j], aB[j]);
            }
        }
    }
    {
        __half2* oa = (__half2*)(ysA + (size_t)n * 64 + oq * 16);
        __half2* ob = (__half2*)(ysB + (size_t)n * 64 + oq * 16);
#pragma unroll
        for (int q = 0; q < 8; ++q) {
            oa[q] = __floats2half2_rn(aA[2 * q], aA[2 * q + 1]);
            ob[q] = __floats2half2_rn(aB[2 * q], aB[2 * q + 1]);
        }
    }
}

// ================= edge kernel: fp16 tables, fp16 payload, 1 atomic/edge =================
__global__ __launch_bounds__(64) void gvp_edge_scatter_kernel(
    const int* __restrict__ ei, const float* __restrict__ edge_s,
    const float* __restrict__ edge_v,
    const __half* __restrict__ ysA, const __half* __restrict__ ysB,
    const __half* __restrict__ va, const __half* __restrict__ vb,
    const float* __restrict__ w1_wh, const float* __restrict__ w1_ws,
    const float* __restrict__ w1_wsb, const float* __restrict__ w1_wv,
    const float* __restrict__ w1_wsv, const float* __restrict__ w1_wsvb,
    const float* __restrict__ w2_wh, const float* __restrict__ w2_ws,
    const float* __restrict__ w2_wsb, const float* __restrict__ w2_wv,
    const float* __restrict__ w2_wsv, const float* __restrict__ w2_wsvb,
    const float* __restrict__ w3_wh, const float* __restrict__ w3_ws,
    const float* __restrict__ w3_wsb, const float* __restrict__ w3_wv,
    const float* __restrict__ w3_wsv, const float* __restrict__ w3_wsvb,
    __half* __restrict__ payload, int* __restrict__ slotCnt,
    int* __restrict__ slotTab, float* __restrict__ accS,
    float* __restrict__ accV, int E)
{
    __shared__ __half rows[64 * 70];
    __half* row = rows + threadIdx.x * 70;
    const int e = blockIdx.x * 64 + threadIdx.x;
    if (e >= E) return;
    const int src = ei[e];
    const int dst = ei[E + e];

    const int slot = atomicAdd(&slotCnt[dst], 1);
    if (slot < 64) slotTab[(size_t)dst * 64 + slot] = e;
    const bool ovf = (slot >= 64);

    const float ev0 = edge_v[(size_t)e * 3 + 0];
    const float ev1 = edge_v[(size_t)e * 3 + 1];
    const float ev2 = edge_v[(size_t)e * 3 + 2];

    float acc[64];
#pragma unroll
    for (int o = 0; o < 64; ++o) acc[o] = 0.0f;
    float pv[12];
#pragma unroll
    for (int i = 0; i < 12; ++i) pv[i] = 0.0f;

    const __half* vaP = va + (size_t)src * 108;
    const __half* vbP = vb + (size_t)dst * 108;
    for (int g = 0; g < 8; ++g) {            // h = 4g..4g+3
        float ca[12];
#pragma unroll
        for (int d = 0; d < 3; ++d) {
            const __half2* pA = (const __half2*)(vaP + d * 36 + 4 * g);
            const __half2* pB = (const __half2*)(vbP + d * 36 + 4 * g);
            float2 a0 = __half22float2(pA[0]);
            float2 a1 = __half22float2(pA[1]);
            float2 b0 = __half22float2(pB[0]);
            float2 b1 = __half22float2(pB[1]);
            ca[0 + d] = a0.x + b0.x;
            ca[3 + d] = a0.y + b0.y;
            ca[6 + d] = a1.x + b1.x;
            ca[9 + d] = a1.y + b1.y;
        }
        const float* weP = w1_wh + 16 * 33 + 4 * g;
        const float* wvP = w1_wv + (4 * g) * 4;
        const float* wsP = w1_ws + (size_t)(288 + 4 * g) * 64;
#pragma unroll
        for (int i = 0; i < 4; ++i) {
            const float we = weP[i];
            const float d0 = ca[3 * i + 0] + ev0 * we;
            const float d1 = ca[3 * i + 1] + ev1 * we;
            const float d2 = ca[3 * i + 2] + ev2 * we;
            const float vn = sqrtf(fmaxf(d0 * d0 + d1 * d1 + d2 * d2, 1e-8f));
            const float* wr = wsP + i * 64;
#pragma unroll
            for (int o = 0; o < 64; ++o) acc[o] = fmaf(vn, wr[o], acc[o]);
#pragma unroll
            for (int vo = 0; vo < 4; ++vo) {
                const float w = wvP[i * 4 + vo];
                pv[vo * 3 + 0] = fmaf(d0, w, pv[vo * 3 + 0]);
                pv[vo * 3 + 1] = fmaf(d1, w, pv[vo * 3 + 1]);
                pv[vo * 3 + 2] = fmaf(d2, w, pv[vo * 3 + 2]);
            }
        }
    }
    {   // tail h = 32
        const float we = w1_wh[16 * 33 + 32];
        const float d0 = __half2float(vaP[0 * 36 + 32]) + __half2float(vbP[0 * 36 + 32]) + ev0 * we;
        const float d1 = __half2float(vaP[1 * 36 + 32]) + __half2float(vbP[1 * 36 + 32]) + ev1 * we;
        const float d2 = __half2float(vaP[2 * 36 + 32]) + __half2float(vbP[2 * 36 + 32]) + ev2 * we;
        const float vn = sqrtf(fmaxf(d0 * d0 + d1 * d1 + d2 * d2, 1e-8f));
        const float* wr = w1_ws + (size_t)320 * 64;
#pragma unroll
        for (int o = 0; o < 64; ++o) acc[o] = fmaf(vn, wr[o], acc[o]);
#pragma unroll
        for (int vo = 0; vo < 4; ++vo) {
            const float w = w1_wv[32 * 4 + vo];
            pv[vo * 3 + 0] = fmaf(d0, w, pv[vo * 3 + 0]);
            pv[vo * 3 + 1] = fmaf(d1, w, pv[vo * 3 + 1]);
            pv[vo * 3 + 2] = fmaf(d2, w, pv[vo * 3 + 2]);
        }
    }

    // ---- add precomputed node terms (fp16 tables)
    {
        const __half2* pa = (const __half2*)(ysA + (size_t)src * 64);
        const __half2* pb = (const __half2*)(ysB + (size_t)dst * 64);
#pragma unroll
        for (int q = 0; q < 32; ++q) {
            float2 xa = __half22float2(pa[q]);
            float2 xb = __half22float2(pb[q]);
            acc[2 * q + 0] += xa.x + xb.x;
            acc[2 * q + 1] += xa.y + xb.y;
        }
    }
    {
        const float4* xs = (const float4*)(edge_s + (size_t)e * 32);
        for (int k4 = 0; k4 < 8; ++k4) { float4 x = xs[k4]; RANK4(x, w1_ws + (size_t)(128 + k4 * 4) * 64); }
    }

    // ---- layer-1 epilogue
    float gp[4] = {0.f, 0.f, 0.f, 0.f};
#pragma unroll
    for (int o = 0; o < 64; ++o) {
        const float s = acc[o] + w1_wsb[o];
        const float sg = sigm(s);
#pragma unroll
        for (int vo = 0; vo < 4; ++vo) gp[vo] = fmaf(sg, w1_wsv[o * 4 + vo], gp[vo]);
        row[o] = __float2half(fmaxf(s, 0.0f));
    }
    float g1[4];
#pragma unroll
    for (int vo = 0; vo < 4; ++vo) g1[vo] = sigm(gp[vo] + w1_wsvb[vo]);
    float v1g[12];
#pragma unroll
    for (int vo = 0; vo < 4; ++vo)
#pragma unroll
        for (int d = 0; d < 3; ++d) v1g[vo * 3 + d] = pv[vo * 3 + d] * g1[vo];
    float vh2[12];
#pragma unroll
    for (int i = 0; i < 12; ++i) vh2[i] = 0.0f;
#pragma unroll
    for (int c = 0; c < 4; ++c)
#pragma unroll
        for (int h = 0; h < 4; ++h) {
            const float w = w2_wh[c * 4 + h];
#pragma unroll
            for (int d = 0; d < 3; ++d) vh2[d * 4 + h] = fmaf(v1g[c * 3 + d], w, vh2[d * 4 + h]);
        }
#pragma unroll
    for (int h = 0; h < 4; ++h) {
        const float ss = vh2[h] * vh2[h] + vh2[4 + h] * vh2[4 + h] + vh2[8 + h] * vh2[8 + h];
        row[64 + h] = __float2half(sqrtf(fmaxf(ss, 1e-8f)));
    }

    // ---- GEMM2
    float acc2[64];
#pragma unroll
    for (int o = 0; o < 64; ++o) acc2[o] = 0.0f;
    for (int k = 0; k < 68; ++k) {
        const float xk = __half2float(row[k]);
        const float* w = w2_ws + k * 64;
#pragma unroll
        for (int o = 0; o < 64; ++o) acc2[o] = fmaf(xk, w[o], acc2[o]);
    }

    // ---- layer-2 epilogue
    float gp2[4] = {0.f, 0.f, 0.f, 0.f};
#pragma unroll
    for (int o = 0; o < 64; ++o) {
        const float s = acc2[o] + w2_wsb[o];
        const float sg = sigm(s);
#pragma unroll
        for (int vo = 0; vo < 4; ++vo) gp2[vo] = fmaf(sg, w2_wsv[o * 4 + vo], gp2[vo]);
        row[o] = __float2half(fmaxf(s, 0.0f));
    }
    float g2[4];
#pragma unroll
    for (int vo = 0; vo < 4; ++vo) g2[vo] = sigm(gp2[vo] + w2_wsvb[vo]);
    float v2g[12];
#pragma unroll
    for (int vo = 0; vo < 4; ++vo)
#pragma unroll
        for (int d = 0; d < 3; ++d) {
            float t = 0.0f;
#pragma unroll
            for (int h = 0; h < 4; ++h) t = fmaf(vh2[d * 4 + h], w2_wv[h * 4 + vo], t);
            v2g[vo * 3 + d] = t * g2[vo];
        }
    float vh3[12];
#pragma unroll
    for (int i = 0; i < 12; ++i) vh3[i] = 0.0f;
#pragma unroll
    for (int c = 0; c < 4; ++c)
#pragma unroll
        for (int h = 0; h < 4; ++h) {
            const float w = w3_wh[c * 4 + h];
#pragma unroll
            for (int d = 0; d < 3; ++d) vh3[d * 4 + h] = fmaf(v2g[c * 3 + d], w, vh3[d * 4 + h]);
        }
#pragma unroll
    for (int h = 0; h < 4; ++h) {
        const float ss = vh3[h] * vh3[h] + vh3[4 + h] * vh3[4 + h] + vh3[8 + h] * vh3[8 + h];
        row[64 + h] = __float2half(sqrtf(fmaxf(ss, 1e-8f)));
    }

    // ---- GEMM3
#pragma unroll
    for (int o = 0; o < 64; ++o) acc[o] = 0.0f;
    for (int k = 0; k < 68; ++k) {
        const float xk = __half2float(row[k]);
        const float* w = w3_ws + k * 64;
#pragma unroll
        for (int o = 0; o < 64; ++o) acc[o] = fmaf(xk, w[o], acc[o]);
    }

    // ---- final epilogue: fp16 payload (packed half2 stores)
    __half2* P2 = (__half2*)(payload + (size_t)e * 80);
    float gp3[4] = {0.f, 0.f, 0.f, 0.f};
    float prev = 0.0f;
#pragma unroll
    for (int o = 0; o < 64; ++o) {
        const float s3 = acc[o] + w3_wsb[o];
#pragma unroll
        for (int vo = 0; vo < 4; ++vo) gp3[vo] = fmaf(s3, w3_wsv[o * 4 + vo], gp3[vo]);
        if (o & 1) P2[o >> 1] = __floats2half2_rn(prev, s3);
        else prev = s3;
        if (ovf) atomicAdd(&accS[(size_t)dst * 64 + o], s3);
    }
    float g3[4];
#pragma unroll
    for (int vo = 0; vo < 4; ++vo) g3[vo] = sigm(gp3[vo] + w3_wsvb[vo]);
    float v3v[12];
#pragma unroll
    for (int vo = 0; vo < 4; ++vo)
#pragma unroll
        for (int d = 0; d < 3; ++d) {
            float t = 0.0f;
#pragma unroll
            for (int h = 0; h < 4; ++h) t = fmaf(vh3[d * 4 + h], w3_wv[h * 4 + vo], t);
            const float val = t * g3[vo];
            v3v[vo * 3 + d] = val;
            if (ovf) atomicAdd(&accV[(size_t)dst * 12 + vo * 3 + d], val);
        }
#pragma unroll
    for (int j = 0; j < 6; ++j) P2[32 + j] = __floats2half2_rn(v3v[2 * j], v3v[2 * j + 1]);
}

// ================= node aggregate + finalize (one wave per node) =================
__global__ __launch_bounds__(256) void node_agg_kernel(
    const __half* __restrict__ payload, const int* __restrict__ slotCnt,
    const int* __restrict__ slotTab, const float* __restrict__ accS,
    const float* __restrict__ accV, const int* __restrict__ mask,
    float* __restrict__ out, int N)
{
    const int gtid = blockIdx.x * 256 + threadIdx.x;
    const int n = gtid >> 6;
    const int lane = threadIdx.x & 63;
    if (n >= N) return;

    const int cnt = slotCnt[n];
    const int m = (cnt < 64) ? cnt : 64;

    int eid_l = (lane < m) ? slotTab[(size_t)n * 64 + lane] : 0;

    float ps[4] = {0.f, 0.f, 0.f, 0.f};
    float pvv[4] = {0.f, 0.f, 0.f, 0.f};
    for (int j = 0; j < m; j += 4) {
#pragma unroll
        for (int u = 0; u < 4; ++u) {
            const int jj = j + u;
            if (jj < m) {
                const int eid = __shfl(eid_l, jj, 64);
                const __half* P = payload + (size_t)eid * 80;
                ps[u] += __half2float(P[lane]);
                if (lane < 12) pvv[u] += __half2float(P[64 + lane]);
            }
        }
    }
    float sS = (ps[0] + ps[1]) + (ps[2] + ps[3]);
    float sV = (pvv[0] + pvv[1]) + (pvv[2] + pvv[3]);
    sS += accS[(size_t)n * 64 + lane];
    if (lane < 12) sV += accV[(size_t)n * 12 + lane];

    const float denom = fmaxf((float)cnt, 1.0f);
    const float mk = (mask[n] != 0) ? 1.0f : 0.0f;

    const float s = sS / denom;
    const float r = (lane < 7) ? __cosf(s) : (lane < 14) ? __sinf(s) : __expf(s);
    out[(size_t)n * 64 + lane] = r * mk;

    const float vm = sV / denom;
    const int vo3 = (lane / 3) * 3;
    const float c0 = __shfl(vm, vo3 + 0, 64);
    const float c1 = __shfl(vm, vo3 + 1, 64);
    const float c2 = __shfl(vm, vo3 + 2, 64);
    if (lane < 12) {
        const float mag = sqrtf(c0 * c0 + c1 * c1 + c2 * c2);
        out[(size_t)N * 64 + (size_t)n * 12 + lane] = (vm / (mag + 1e-8f)) * mk;
    }
}

extern "C" void kernel_launch(void* const* d_in, const int* in_sizes, int n_in,
                              void* d_out, int out_size, void* d_ws, size_t ws_size,
                              hipStream_t stream)
{
    const float* node_s = (const float*)d_in[0];
    const float* node_v = (const float*)d_in[1];
    const int*   ei     = (const int*)d_in[2];
    const float* edge_s = (const float*)d_in[3];
    const float* edge_v = (const float*)d_in[4];
    const int*   mask   = (const int*)d_in[5];
    const float* w1_wh  = (const float*)d_in[6];
    const float* w1_ws  = (const float*)d_in[7];
    const float* w1_wsb = (const float*)d_in[8];
    const float* w1_wv  = (const float*)d_in[9];
    const float* w1_wsv = (const float*)d_in[10];
    const float* w1_wsvb= (const float*)d_in[11];
    const float* w2_wh  = (const float*)d_in[12];
    const float* w2_ws  = (const float*)d_in[13];
    const float* w2_wsb = (const float*)d_in[14];
    const float* w2_wv  = (const float*)d_in[15];
    const float* w2_wsv = (const float*)d_in[16];
    const float* w2_wsvb= (const float*)d_in[17];
    const float* w3_wh  = (const float*)d_in[18];
    const float* w3_ws  = (const float*)d_in[19];
    const float* w3_wsb = (const float*)d_in[20];
    const float* w3_wv  = (const float*)d_in[21];
    const float* w3_wsv = (const float*)d_in[22];
    const float* w3_wsvb= (const float*)d_in[23];

    const int N = in_sizes[0] / 128;   // 20000
    const int E = in_sizes[3] / 32;    // 320000

    float* out = (float*)d_out;
    float* ws  = (float*)d_ws;

    // ws layout (float offsets):
    //   ysAH N*32 | ysBH N*32 | vaH N*54 | vbH N*54 |
    //   slotCnt N | slotTab N*64 | accS N*64 | accV N*12 | payloadH E*40
    const size_t oYA = 0;
    const size_t oYB = (size_t)N * 32;
    const size_t oVA = (size_t)N * 64;
    const size_t oVB = (size_t)N * 118;
    const size_t oSC = (size_t)N * 172;
    const size_t oST = (size_t)N * 173;
    const size_t oAS = (size_t)N * 237;
    const size_t oAV = (size_t)N * 301;
    const size_t oPL = (size_t)N * 313;
    const size_t needF = oPL + (size_t)E * 40;    // ~76 MB

    if (ws_size >= needF * sizeof(float)) {
        __half* ysAH = (__half*)(ws + oYA);
        __half* ysBH = (__half*)(ws + oYB);
        __half* vaH  = (__half*)(ws + oVA);
        __half* vbH  = (__half*)(ws + oVB);
        int* slotCnt = (int*)(ws + oSC);
        int* slotTab = (int*)(ws + oST);
        float* accS  = ws + oAS;
        float* accV  = ws + oAV;
        __half* payloadH = (__half*)(ws + oPL);

        hipMemsetAsync(slotCnt, 0, (size_t)N * sizeof(int), stream);
        hipMemsetAsync(accS, 0, (size_t)N * 76 * sizeof(float), stream);  // accS+accV contiguous

        node_pre_kernel<<<((N + 63) / 64) * 4, 64, 0, stream>>>(
            node_s, node_v, w1_wh, w1_ws,
            ysAH, ysBH, vaH, vbH, N);
        gvp_edge_scatter_kernel<<<(E + 63) / 64, 64, 0, stream>>>(
            ei, edge_s, edge_v,
            ysAH, ysBH, vaH, vbH,
            w1_wh, w1_ws, w1_wsb, w1_wv, w1_wsv, w1_wsvb,
            w2_wh, w2_ws, w2_wsb, w2_wv, w2_wsv, w2_wsvb,
            w3_wh, w3_ws, w3_wsb, w3_wv, w3_wsv, w3_wsvb,
            payloadH, slotCnt, slotTab, accS, accV, E);
        node_agg_kernel<<<(N * 64 + 255) / 256, 256, 0, stream>>>(
            payloadH, slotCnt, slotTab, accS, accV, mask, out, N);
    }
}